// Round 20
// baseline (1297.201 us; speedup 1.0000x reference)
//
#include <hip/hip_runtime.h>

// EntityAttentionRNNMsgAgent — fused MI355X implementation.
// r20 = r19 + (1) k1_all split into k1_b2 + k1_gate: branch2 goes 1 item/block
// (LDS 152K->76K => 2 blocks/CU, 16 waves/CU; Qful/out-proj via 16x16
// 2-tiles/wave; phase1/KV keep 32x32), gate role unchanged in its own kernel;
// (2) k3 at 1024 threads (16 waves x 3 col-tiles, 4 dims/thread elementwise).
// k0 / k0w / k2 / k4 byte-identical to r19 (1143.6us verified).

#define DEV __device__ __forceinline__

typedef _Float16 f16x8 __attribute__((ext_vector_type(8)));
typedef _Float16 f16x4 __attribute__((ext_vector_type(4)));
typedef float    f32x4 __attribute__((ext_vector_type(4)));
typedef float    f32x16 __attribute__((ext_vector_type(16)));

DEV f32x4 mfma16(f16x8 a, f16x8 b, f32x4 c){
  return __builtin_amdgcn_mfma_f32_16x16x32_f16(a, b, c, 0, 0, 0);
}
DEV f32x16 mfma32(f16x8 a, f16x8 b, f32x16 c){
  return __builtin_amdgcn_mfma_f32_32x32x16_f16(a, b, c, 0, 0, 0);
}

// A/B fragment pair for optional split-precision (MODE=1: value = hi + lo)
template<int MODE> struct AB {
  f16x8 hi, lo;
  DEV void mf(const AB& b, f32x4& c) const {
    if constexpr (MODE){
      c = mfma16(lo, b.hi, c);
      c = mfma16(hi, b.lo, c);
    }
    c = mfma16(hi, b.hi, c);
  }
};

template<int MODE> DEV AB<MODE> ldW(const _Float16* p, int losz){
  AB<MODE> r; r.hi = *(const f16x8*)p;
  if constexpr (MODE) r.lo = *(const f16x8*)(p + losz);
  return r;
}
template<int MODE> DEV AB<MODE> ldL(const _Float16* ph, const _Float16* pl){
  AB<MODE> r; r.hi = *(const f16x8*)ph;
  if constexpr (MODE) r.lo = *(const f16x8*)pl;
  return r;
}
template<int MODE> DEV AB<MODE> ldF(const float* p){
  AB<MODE> r;
  f32x4 v0 = *(const f32x4*)p, v1 = *(const f32x4*)(p + 4);
#pragma unroll
  for (int i = 0; i < 4; ++i){
    float a = v0[i], b = v1[i];
    _Float16 ah = (_Float16)a, bh = (_Float16)b;
    r.hi[i] = ah; r.hi[i+4] = bh;
    if constexpr (MODE){
      r.lo[i]   = (_Float16)(a - (float)ah);
      r.lo[i+4] = (_Float16)(b - (float)bh);
    }
  }
  return r;
}
template<int MODE> DEV void stL(_Float16* ph, _Float16* pl, int idx, float v){
  _Float16 h = (_Float16)v;
  ph[idx] = h;
  if constexpr (MODE) pl[idx] = (_Float16)(v - (float)h);
}

// ---------------------------------------------------------------- K0: weights
struct WJobs {
  const float* src[15];
  unsigned off[15];
  int K[15], N[15], mode[15];
};

__global__ __launch_bounds__(256) void k0_conv(WJobs jb, char* ws){
  const int job = blockIdx.y;
  const int K = jb.K[job], N = jb.N[job];
  const int total = K * N;
  _Float16* dh = (_Float16*)(ws + jb.off[job]);
  const float* src = jb.src[job];
  const int m = jb.mode[job];
  for (int idx = blockIdx.x*256 + threadIdx.x; idx < total; idx += gridDim.x*256){
    int n = idx / K, k = idx - n*K;
    float v = src[(size_t)k*N + n];
    _Float16 h = (_Float16)v;
    dh[idx] = h;
    if (m) dh[total + idx] = (_Float16)(v - (float)h);
  }
}

// ------------------------------------------------- K0w: gate-tail precompute
__global__ __launch_bounds__(256) void k0w_gate(
    const float* __restrict__ Wout, const float* __restrict__ Wg2,
    const float* __restrict__ bo,   const float* __restrict__ Win,
    _Float16* __restrict__ wveff, float* __restrict__ beff)
{
  __shared__ float weff_s[256*2];
  const int tid = threadIdx.x;
  {
    float a0 = 0.f, a1 = 0.f;
    const float* wr = Wout + (size_t)tid*256;
    for (int f = 0; f < 256; ++f){ float x = wr[f]; a0 += x*Wg2[2*f]; a1 += x*Wg2[2*f+1]; }
    weff_s[tid*2] = a0; weff_s[tid*2+1] = a1;
  }
  if (tid < 2){
    float s = 0.f;
    for (int f = 0; f < 256; ++f) s += bo[f]*Wg2[2*f + tid];
    beff[tid] = s;
  }
  __syncthreads();
  {
    const int j = tid;
    for (int n = 0; n < 16; ++n){
      float v = 0.f;
      if (n < 8){
        int h = n >> 1, c = n & 1;
        const float* wr = Win + (size_t)j*768 + 512 + h*64;
        const float* we = weff_s + (h*64)*2 + c;
        for (int d = 0; d < 64; ++d) v += wr[d]*we[2*d];
      }
      _Float16 hi = (_Float16)v;
      wveff[n*256 + j] = hi;
      wveff[16*256 + n*256 + j] = (_Float16)(v - (float)hi);
    }
  }
}

// -------------------------------- K1_b2: branch2 attention, 1 item per block
// LDS 76032 B -> 2 blocks/CU (16 waves). blocks 0..2047 branch a, 2048..4095 b.
__global__ __launch_bounds__(512) void k1_b2(
    const float* __restrict__ ent, const float* __restrict__ om, const float* __restrict__ em,
    const _Float16* __restrict__ W1a, const float* __restrict__ b1a,
    const _Float16* __restrict__ WINa,
    const _Float16* __restrict__ WOUTa, const float* __restrict__ boa,
    float* __restrict__ x2outa,
    const _Float16* __restrict__ W1b, const float* __restrict__ b1b,
    const _Float16* __restrict__ WINb,
    const _Float16* __restrict__ WOUTb, const float* __restrict__ bob,
    float* __restrict__ x2outb)
{
  const int tid = threadIdx.x;
  const int w = tid >> 6, lg = (tid >> 4) & 3, li = tid & 15;
  const int l = tid & 63;
  const int r32 = l & 31, kh = (l >> 5)*8;
  extern __shared__ char smem[];

  const int br = blockIdx.x >> 11;
  const int b  = blockIdx.x & 2047;
  const _Float16* W1   = br ? W1b   : W1a;
  const float*    b1   = br ? b1b   : b1a;
  const _Float16* WIN  = br ? WINb  : WINa;
  const _Float16* WOUT = br ? WOUTb : WOUTa;
  const float*    bo   = br ? bob   : boa;
  float*          x2out= br ? x2outb: x2outa;

  // LDS (bytes): x1 0, Ks 33792, Vs 43008, Qful 52224, lgs 60672,
  //              Ps 65280, outp 67584; total 76032
  _Float16* x1   = (_Float16*)smem;
  _Float16* Ks   = (_Float16*)(smem + 33792);
  _Float16* Vs   = (_Float16*)(smem + 43008);
  _Float16* Qful = (_Float16*)(smem + 52224);
  float*    lgs  = (float*)(smem + 60672);
  _Float16* Ps   = (_Float16*)(smem + 65280);
  _Float16* outp = (_Float16*)(smem + 67584);

  { // phase 1: x1 = relu(ent @ W1 + b1) via 32x32x16; wave: mt=w&1, 2 n-tiles
    const int mt = w & 1, ntb = (w >> 1)*2;
    f32x16 acc0 = 0.f, acc1 = 0.f;
#pragma unroll
    for (int kk = 0; kk < 6; ++kk){
      AB<0> a = ldF<0>(ent + ((size_t)b*64 + mt*32 + r32)*96 + kk*16 + kh);
      f16x8 B0 = *(const f16x8*)(W1 + (size_t)((ntb + 0)*32 + r32)*96 + kk*16 + kh);
      f16x8 B1 = *(const f16x8*)(W1 + (size_t)((ntb + 1)*32 + r32)*96 + kk*16 + kh);
      acc0 = mfma32(a.hi, B0, acc0);
      acc1 = mfma32(a.hi, B1, acc1);
    }
#pragma unroll
    for (int s = 0; s < 2; ++s){
      const f32x16& ac = s ? acc1 : acc0;
      int col = (ntb + s)*32 + r32;
      float bias = b1[col];
#pragma unroll
      for (int reg = 0; reg < 16; ++reg){
        int row = (reg & 3) + 8*(reg >> 2) + 4*(l >> 5);
        x1[(mt*32 + row)*264 + col] = (_Float16)fmaxf(ac[reg] + bias, 0.f);
      }
    }
  }
  __syncthreads();

  { // Qful = x1[rows 0..15] @ Wq via 16x16; wave -> n-tiles {w, w+8}
#pragma unroll
    for (int s = 0; s < 2; ++s){
      int nt = w + s*8;
      f32x4 acc = 0.f;
      for (int kk = 0; kk < 8; ++kk){
        f16x8 A = *(const f16x8*)(x1 + li*264 + kk*32 + lg*8);
        f16x8 B = *(const f16x8*)(WIN + (size_t)(nt*16 + li)*256 + kk*32 + lg*8);
        acc = mfma16(A, B, acc);
      }
#pragma unroll
      for (int j = 0; j < 4; ++j)
        Qful[(4*lg + j)*264 + nt*16 + li] = (_Float16)acc[j];
    }
  }
  __syncthreads();

  for (int h = 0; h < 4; ++h){
    if (w < 4){ // K tile (kt, dt), 32x32
      const int kt = w >> 1, dt = w & 1;
      f32x16 acc = 0.f;
      for (int kk = 0; kk < 16; ++kk){
        f16x8 A = *(const f16x8*)(x1 + (kt*32 + r32)*264 + kk*16 + kh);
        f16x8 B = *(const f16x8*)(WIN + (size_t)(256 + 64*h + dt*32 + r32)*256 + kk*16 + kh);
        acc = mfma32(A, B, acc);
      }
#pragma unroll
      for (int reg = 0; reg < 16; ++reg){
        int row = (reg & 3) + 8*(reg >> 2) + 4*(l >> 5);
        Ks[(kt*32 + row)*72 + dt*32 + r32] = (_Float16)acc[reg];
      }
    } else { // V tile, transposed store
      const int wv = w - 4;
      const int kt = wv >> 1, dt = wv & 1;
      f32x16 acc = 0.f;
      for (int kk = 0; kk < 16; ++kk){
        f16x8 A = *(const f16x8*)(x1 + (kt*32 + r32)*264 + kk*16 + kh);
        f16x8 B = *(const f16x8*)(WIN + (size_t)(512 + 64*h + dt*32 + r32)*256 + kk*16 + kh);
        acc = mfma32(A, B, acc);
      }
#pragma unroll
      for (int rr = 0; rr < 4; ++rr){
        f16x4 p0;
#pragma unroll
        for (int q4 = 0; q4 < 4; ++q4) p0[q4] = (_Float16)acc[rr*4 + q4];
        int key = kt*32 + rr*8 + 4*(l >> 5);
        *(f16x4*)(Vs + (dt*32 + r32)*72 + key) = p0;
      }
    }
    __syncthreads();
    if (w < 4){ // logits
      f32x4 acc = 0.f;
#pragma unroll
      for (int kk = 0; kk < 2; ++kk){
        f16x8 A = *(const f16x8*)(Qful + li*264 + 64*h + kk*32 + lg*8);
        f16x8 B = *(const f16x8*)(Ks + (16*w + li)*72 + kk*32 + lg*8);
        acc = mfma16(A, B, acc);
      }
#pragma unroll
      for (int j = 0; j < 4; ++j){
        int q = 4*lg + j, key = 16*w + li;
        float v = acc[j] * 0.125f;
        float m = om[((size_t)b*64 + q)*64 + key];
        if (m > 0.f) v = -1e9f;
        lgs[q*72 + key] = v;
      }
    }
    __syncthreads();
    if (tid < 256){ // softmax
      int q = tid >> 4, i16 = tid & 15;
      float pv[4], mx = -3e38f;
#pragma unroll
      for (int u = 0; u < 4; ++u){ pv[u] = lgs[q*72 + i16 + 16*u]; mx = fmaxf(mx, pv[u]); }
#pragma unroll
      for (int d = 1; d < 16; d <<= 1) mx = fmaxf(mx, __shfl_xor(mx, d, 16));
      float s = 0.f;
#pragma unroll
      for (int u = 0; u < 4; ++u){ pv[u] = expf(pv[u] - mx); s += pv[u]; }
#pragma unroll
      for (int d = 1; d < 16; d <<= 1) s += __shfl_xor(s, d, 16);
#pragma unroll
      for (int u = 0; u < 4; ++u){
        int key = i16 + 16*u;
        float m = om[((size_t)b*64 + q)*64 + key];
        Ps[q*72 + key] = (_Float16)((pv[u]/s)*(1.f - m));
      }
    }
    __syncthreads();
    if (w < 4){ // PV
      f32x4 acc = 0.f;
#pragma unroll
      for (int kk = 0; kk < 2; ++kk){
        f16x8 A = *(const f16x8*)(Ps + li*72 + kk*32 + lg*8);
        f16x8 B = *(const f16x8*)(Vs + (16*w + li)*72 + kk*32 + lg*8);
        acc = mfma16(A, B, acc);
      }
#pragma unroll
      for (int j = 0; j < 4; ++j)
        outp[(4*lg + j)*264 + 64*h + 16*w + li] = (_Float16)acc[j];
    }
    __syncthreads();
  }

  { // out-proj via 16x16; wave -> n-tiles {w, w+8}
#pragma unroll
    for (int s = 0; s < 2; ++s){
      int nt = w + s*8;
      f32x4 acc = 0.f;
      for (int kk = 0; kk < 8; ++kk){
        f16x8 A = *(const f16x8*)(outp + li*264 + kk*32 + lg*8);
        f16x8 B = *(const f16x8*)(WOUT + (size_t)(nt*16 + li)*256 + kk*32 + lg*8);
        acc = mfma16(A, B, acc);
      }
      int col = nt*16 + li;
      float bias = bo[col];
#pragma unroll
      for (int j = 0; j < 4; ++j){
        int q = 4*lg + j;
        float v = (acc[j] + bias) * (1.f - em[(size_t)b*64 + q]);
        x2out[((size_t)b*16 + q)*256 + col] = v;
      }
    }
  }
}

// ------------------------------------------ K1_gate: gate role (own kernel)
__global__ __launch_bounds__(512) void k1_gate(
    const float* __restrict__ ent, const float* __restrict__ om, const float* __restrict__ em,
    const _Float16* __restrict__ W1g, const float* __restrict__ b1g,
    const _Float16* __restrict__ WINg,
    const _Float16* __restrict__ WVEFF,
    const float* __restrict__ beff, const float* __restrict__ gb2,
    float* __restrict__ og, float* __restrict__ gate)
{
  const int tid = threadIdx.x;
  const int w = tid >> 6, lg = (tid >> 4) & 3, li = tid & 15;
  extern __shared__ char smem[];

  constexpr int W1SZ = 96*256, WINSZ = 256*768, WVSZ = 16*256;
  const int b = blockIdx.x;
  const int l = tid & 63;
  const int r32 = l & 31, kh = (l >> 5)*8;

  char* sp = smem;
  _Float16* x1h = (_Float16*)sp; sp += 64*264*2;
  _Float16* x1l = (_Float16*)sp; sp += 64*264*2;
  _Float16* Kh  = (_Float16*)sp; sp += 64*72*2;
  _Float16* Kl  = (_Float16*)sp; sp += 64*72*2;
  _Float16* Qh  = (_Float16*)sp; sp += 16*264*2;
  _Float16* Ql  = (_Float16*)sp; sp += 16*264*2;
  float*    lgs = (float*)sp;    sp += 16*72*4;
  float*    Ps  = (float*)sp;    sp += 16*66*4;
  float*    v2s = (float*)sp;    sp += 64*18*4;
  float*  ogacc = (float*)sp;    sp += 32*4;
  float*  Kpart = (float*)sp;    sp += 8192*4;

  { // phase 1: x1 = relu(ent @ W1g + b1g), 32x32 split-2
    const int mt = w & 1, ntb = (w >> 1)*2;
    f32x16 acc0 = 0.f, acc1 = 0.f;
#pragma unroll
    for (int kk = 0; kk < 6; ++kk){
      AB<1> a = ldF<1>(ent + ((size_t)b*64 + mt*32 + r32)*96 + kk*16 + kh);
#pragma unroll
      for (int s = 0; s < 2; ++s){
        const _Float16* bp = W1g + (size_t)((ntb + s)*32 + r32)*96 + kk*16 + kh;
        f16x8 Bh = *(const f16x8*)bp;
        f16x8 Bl = *(const f16x8*)(bp + W1SZ);
        f32x16& ac = s ? acc1 : acc0;
        ac = mfma32(a.lo, Bh, ac);
        ac = mfma32(a.hi, Bl, ac);
        ac = mfma32(a.hi, Bh, ac);
      }
    }
#pragma unroll
    for (int s = 0; s < 2; ++s){
      const f32x16& ac = s ? acc1 : acc0;
      int col = (ntb + s)*32 + r32;
      float bias = b1g[col];
#pragma unroll
      for (int reg = 0; reg < 16; ++reg){
        int row = (reg & 3) + 8*(reg >> 2) + 4*(l >> 5);
        stL<1>(x1h, x1l, (mt*32 + row)*264 + col, fmaxf(ac[reg] + bias, 0.f));
      }
    }
  }
  if (tid < 32) ogacc[tid] = 0.f;
  __syncthreads();

  { // phase 2: Qfull (16x16 split-2), v2
#pragma unroll
    for (int s = 0; s < 2; ++s){
      int nt = w + s*8;
      f32x4 acc = 0.f;
      for (int kk = 0; kk < 8; ++kk){
        int ao = li*264 + kk*32 + lg*8;
        AB<1> a = ldL<1>(x1h + ao, x1l + ao);
        AB<1> bb = ldW<1>(WINg + (size_t)(nt*16 + li)*256 + kk*32 + lg*8, WINSZ);
        a.mf(bb, acc);
      }
#pragma unroll
      for (int j = 0; j < 4; ++j)
        stL<1>(Qh, Ql, (4*lg + j)*264 + nt*16 + li, acc[j]);
    }
    if (w < 4){
      f32x4 acc = 0.f;
      for (int kk = 0; kk < 8; ++kk){
        int ao = (w*16 + li)*264 + kk*32 + lg*8;
        AB<1> a = ldL<1>(x1h + ao, x1l + ao);
        AB<1> bb = ldW<1>(WVEFF + (size_t)li*256 + kk*32 + lg*8, WVSZ);
        a.mf(bb, acc);
      }
#pragma unroll
      for (int j = 0; j < 4; ++j)
        v2s[(w*16 + 4*lg + j)*18 + li] = acc[j];
    }
  }
  __syncthreads();

  for (int h = 0; h < 4; ++h){
    { // K_h partials: 32x32 split-2, tiles x k-halves across 8 waves
      const int t = w & 3, kt = t >> 1, dt = t & 1, khalf = w >> 2;
      f32x16 acc = 0.f;
#pragma unroll
      for (int k8 = 0; k8 < 8; ++k8){
        int ko = (khalf*8 + k8)*16 + kh;
        int ao = (kt*32 + r32)*264 + ko;
        f16x8 ah = *(const f16x8*)(x1h + ao);
        f16x8 al = *(const f16x8*)(x1l + ao);
        const _Float16* bp = WINg + (size_t)(256 + h*64 + dt*32 + r32)*256 + ko;
        f16x8 Bh = *(const f16x8*)bp;
        f16x8 Bl = *(const f16x8*)(bp + WINSZ);
        acc = mfma32(al, Bh, acc);
        acc = mfma32(ah, Bl, acc);
        acc = mfma32(ah, Bh, acc);
      }
#pragma unroll
      for (int reg = 0; reg < 16; ++reg){
        int row = (reg & 3) + 8*(reg >> 2) + 4*(l >> 5);
        Kpart[((khalf*4 + t)*32 + row)*32 + r32] = acc[reg];
      }
    }
    __syncthreads();
    { // reduce k-halves -> Kh/Kl
      for (int e = tid; e < 4096; e += 512){
        float s2 = Kpart[e] + Kpart[4096 + e];
        int t2 = e >> 10, idx = e & 1023, row = idx >> 5, col = idx & 31;
        stL<1>(Kh, Kl, ((t2 >> 1)*32 + row)*72 + (t2 & 1)*32 + col, s2);
      }
    }
    __syncthreads();
    if (w < 4){ // logits
      f32x4 acc = 0.f;
#pragma unroll
      for (int kk = 0; kk < 2; ++kk){
        int ao = li*264 + h*64 + kk*32 + lg*8;
        AB<1> a = ldL<1>(Qh + ao, Ql + ao);
        int bo_ = (16*w + li)*72 + kk*32 + lg*8;
        AB<1> bb = ldL<1>(Kh + bo_, Kl + bo_);
        a.mf(bb, acc);
      }
#pragma unroll
      for (int j = 0; j < 4; ++j){
        int q = 4*lg + j, key = 16*w + li;
        float v = acc[j] * 0.125f;
        float m = om[((size_t)b*64 + q)*64 + key];
        if (m > 0.f) v = -1e9f;
        lgs[q*72 + key] = v;
      }
    }
    __syncthreads();
    if (tid < 256){ // softmax
      int q = tid >> 4, i16 = tid & 15;
      float pv[4], mx = -3e38f;
#pragma unroll
      for (int u = 0; u < 4; ++u){ pv[u] = lgs[q*72 + i16 + 16*u]; mx = fmaxf(mx, pv[u]); }
#pragma unroll
      for (int d = 1; d < 16; d <<= 1) mx = fmaxf(mx, __shfl_xor(mx, d, 16));
      float s = 0.f;
#pragma unroll
      for (int u = 0; u < 4; ++u){ pv[u] = expf(pv[u] - mx); s += pv[u]; }
#pragma unroll
      for (int d = 1; d < 16; d <<= 1) s += __shfl_xor(s, d, 16);
#pragma unroll
      for (int u = 0; u < 4; ++u){
        int key = i16 + 16*u;
        float m = om[((size_t)b*64 + q)*64 + key];
        Ps[q*66 + key] = (pv[u]/s)*(1.f - m);
      }
    }
    __syncthreads();
    if (tid < 256){ // og += P_h . v2_h
      int q = tid >> 4, l16 = tid & 15;
      float a0 = 0.f, a1 = 0.f;
#pragma unroll
      for (int u = 0; u < 4; ++u){
        int k = l16 + 16*u;
        float p2 = Ps[q*66 + k];
        a0 += p2 * v2s[k*18 + h*2];
        a1 += p2 * v2s[k*18 + h*2 + 1];
      }
#pragma unroll
      for (int d = 1; d < 16; d <<= 1){ a0 += __shfl_xor(a0, d, 16); a1 += __shfl_xor(a1, d, 16); }
      if (l16 == 0){ ogacc[q*2] += a0; ogacc[q*2 + 1] += a1; }
    }
    __syncthreads();
  }
  if (tid < 16){
    int q = tid;
    float am = em[(size_t)b*64 + q];
    float g0 = (1.f - am)*(ogacc[2*q]     + beff[0]) + gb2[0];
    float g1 = (1.f - am)*(ogacc[2*q + 1] + beff[1]) + gb2[1];
    og[((size_t)b*16 + q)*2]     = g0;
    og[((size_t)b*16 + q)*2 + 1] = g1;
    gate[(size_t)b*16 + q] = (g1 > g0) ? 1.f : 0.f;
  }
}

// ------------------- K2: gate, global attention, fc2, gi — 2 items/block
__global__ __launch_bounds__(256) void k2_global(
    const float* __restrict__ em,
    const float* __restrict__ x2, const float* __restrict__ x2m,
    const float* __restrict__ gate,
    const _Float16* __restrict__ GMIN, const _Float16* __restrict__ GMOUT, const float* __restrict__ gob,
    const _Float16* __restrict__ FC2T, const float* __restrict__ fc2b,
    const _Float16* __restrict__ GIHT, const float* __restrict__ gib,
    float* __restrict__ gi)
{
  const int p = blockIdx.x;
  const int tid = threadIdx.x;
  const int w = tid >> 6, lg = (tid >> 4) & 3, li = tid & 15;
  const int l = tid & 63;
  const int r32 = l & 31, kh = (l >> 5)*8;

  extern __shared__ char smem[];
  float*    gate_s = (float*)smem;
  _Float16* gm_s   = (_Float16*)(smem + 128);
  float*    lg2    = (float*)(smem + 17024);
  _Float16* P2     = (_Float16*)(smem + 20096);
  _Float16* outp   = (_Float16*)(smem + 22656);
  _Float16* x3_s   = (_Float16*)(smem + 39552);
  _Float16* Vtall  = (_Float16*)(smem + 56448);
  _Float16* Qall   = (_Float16*)(smem + 97408);
  _Float16* Kall   = (_Float16*)(smem + 114304);
  _Float16* cat_s  = (_Float16*)(smem + 97408);   // overlay

  if (tid < 32){
    int it = tid >> 4, q = tid & 15;
    gate_s[it*16 + q] = gate[(size_t)(2*p + it)*16 + q];
  }
  __syncthreads();
#pragma unroll
  for (int it = 0; it < 2; ++it){
    const int b = 2*p + it;
    for (int idx = tid; idx < 4096; idx += 256){
      int q = idx >> 8, d = idx & 255;
      gm_s[it*4224 + q*264 + d] = (_Float16)(x2m[((size_t)b*16 + q)*256 + d] * gate_s[it*16 + q]);
    }
  }
  for (int idx = tid; idx < 10240; idx += 256) ((unsigned*)Vtall)[idx] = 0u;
  for (int idx = tid; idx < 2*16*40; idx += 256) P2[idx] = (_Float16)0.f;
  __syncthreads();

  { // QKVall = gm_stacked(32x256) @ GMIN(768x256); wave -> n-tiles {6w..6w+5}
    const int itq = r32 >> 4, qr = r32 & 15;
#pragma unroll
    for (int s = 0; s < 6; ++s){
      int nt = 6*w + s;
      f32x16 acc = 0.f;
      for (int kk = 0; kk < 16; ++kk){
        f16x8 A = *(const f16x8*)(gm_s + itq*4224 + qr*264 + kk*16 + kh);
        f16x8 B = *(const f16x8*)(GMIN + (size_t)(nt*32 + r32)*256 + kk*16 + kh);
        acc = mfma32(A, B, acc);
      }
      int sec = nt >> 3;
      int hcol = (nt & 7)*32 + r32;
#pragma unroll
      for (int reg = 0; reg < 16; ++reg){
        int row = (reg & 3) + 8*(reg >> 2) + 4*(l >> 5);
        int it2 = row >> 4, q2 = row & 15;
        _Float16 v = (_Float16)acc[reg];
        if (sec == 0)      Qall[it2*4224 + q2*264 + hcol] = v;
        else if (sec == 1) Kall[it2*4224 + q2*264 + hcol] = v;
        else               Vtall[it2*10240 + hcol*40 + q2] = v;
      }
    }
  }
  __syncthreads();

  for (int h = 0; h < 4; ++h){
    if (w < 2){
      const int it = w, b = 2*p + it;
      f32x4 acc = 0.f;
#pragma unroll
      for (int kk = 0; kk < 2; ++kk){
        f16x8 A = *(const f16x8*)(Qall + it*4224 + li*264 + 64*h + kk*32 + lg*8);
        f16x8 B = *(const f16x8*)(Kall + it*4224 + li*264 + 64*h + kk*32 + lg*8);
        acc = mfma16(A, B, acc);
      }
      float amk = em[(size_t)b*64 + li];
#pragma unroll
      for (int j = 0; j < 4; ++j){
        int q = 4*lg + j;
        float amq = em[(size_t)b*64 + q];
        float m = 1.f - (1.f - amq)*(1.f - amk);
        float v = acc[j]*0.125f;
        if (m > 0.f) v = -1e9f;
        lg2[it*384 + q*24 + li] = v;
      }
    }
    __syncthreads();
    {
      int q = tid >> 4, key = tid & 15;
#pragma unroll
      for (int it = 0; it < 2; ++it){
        const int b = 2*p + it;
        float v = lg2[it*384 + q*24 + key];
        float mx = v;
#pragma unroll
        for (int d = 1; d < 16; d <<= 1) mx = fmaxf(mx, __shfl_xor(mx, d, 16));
        float pe = expf(v - mx);
        float s = pe;
#pragma unroll
        for (int d = 1; d < 16; d <<= 1) s += __shfl_xor(s, d, 16);
        float amq = em[(size_t)b*64 + q], amk = em[(size_t)b*64 + key];
        float m = 1.f - (1.f - amq)*(1.f - amk);
        P2[it*640 + q*40 + key] = (_Float16)((pe/s)*(1.f - m));
      }
    }
    __syncthreads();
    {
#pragma unroll
      for (int it = 0; it < 2; ++it){
        f32x4 acc = 0.f;
        f16x8 A = *(const f16x8*)(P2 + it*640 + li*40 + lg*8);
        f16x8 B = *(const f16x8*)(Vtall + it*10240 + (size_t)(64*h + 16*w + li)*40 + lg*8);
        acc = mfma16(A, B, acc);
#pragma unroll
        for (int j = 0; j < 4; ++j)
          outp[it*4224 + (4*lg + j)*264 + 64*h + 16*w + li] = (_Float16)acc[j];
      }
    }
    __syncthreads();
  }
  { // gmsg out-proj stacked M=32; also stage x2 -> cat[:,0:256]
    const int ito = r32 >> 4, qr = r32 & 15;
#pragma unroll
    for (int s = 0; s < 2; ++s){
      int nt = 2*w + s;
      f32x16 acc = 0.f;
      for (int kk = 0; kk < 16; ++kk){
        f16x8 A = *(const f16x8*)(outp + ito*4224 + qr*264 + kk*16 + kh);
        f16x8 B = *(const f16x8*)(GMOUT + (size_t)(nt*32 + r32)*256 + kk*16 + kh);
        acc = mfma32(A, B, acc);
      }
      int col = nt*32 + r32;
      float bias = gob[col];
#pragma unroll
      for (int reg = 0; reg < 16; ++reg){
        int row = (reg & 3) + 8*(reg >> 2) + 4*(l >> 5);
        int it2 = row >> 4, q2 = row & 15;
        float m = 1.f - em[(size_t)(2*p + it2)*64 + q2];
        cat_s[it2*8320 + q2*520 + 256 + col] = (_Float16)((acc[reg] + bias)*m);
      }
    }
#pragma unroll
    for (int it = 0; it < 2; ++it){
      const int b = 2*p + it;
      for (int idx = tid; idx < 4096; idx += 256){
        int q = idx >> 8, d = idx & 255;
        cat_s[it*8320 + q*520 + d] = (_Float16)(x2[((size_t)b*16 + q)*256 + d]);
      }
    }
  }
  __syncthreads();
  { // x3 = relu(cat @ fc2 + b) stacked M=32, K=512
    const int ito = r32 >> 4, qr = r32 & 15;
#pragma unroll
    for (int s = 0; s < 2; ++s){
      int nt = 2*w + s;
      f32x16 acc = 0.f;
      for (int kk = 0; kk < 32; ++kk){
        f16x8 A = *(const f16x8*)(cat_s + ito*8320 + qr*520 + kk*16 + kh);
        f16x8 B = *(const f16x8*)(FC2T + (size_t)(nt*32 + r32)*512 + kk*16 + kh);
        acc = mfma32(A, B, acc);
      }
      int col = nt*32 + r32;
      float bias = fc2b[col];
#pragma unroll
      for (int reg = 0; reg < 16; ++reg){
        int row = (reg & 3) + 8*(reg >> 2) + 4*(l >> 5);
        int it2 = row >> 4, q2 = row & 15;
        x3_s[it2*4224 + q2*264 + col] = (_Float16)fmaxf(acc[reg] + bias, 0.f);
      }
    }
  }
  __syncthreads();
  { // gi stacked M=32; wave -> n-tiles {6w .. 6w+5}, N=768
    const int r0 = ((2*p) >> 6)*16, t0 = (2*p) & 63;
    const int ito = r32 >> 4, qr = r32 & 15;
#pragma unroll
    for (int s = 0; s < 6; ++s){
      int nt = 6*w + s;
      f32x16 acc = 0.f;
      for (int kk = 0; kk < 16; ++kk){
        f16x8 A = *(const f16x8*)(x3_s + ito*4224 + qr*264 + kk*16 + kh);
        f16x8 B = *(const f16x8*)(GIHT + (size_t)(nt*32 + r32)*256 + kk*16 + kh);
        acc = mfma32(A, B, acc);
      }
      int col = nt*32 + r32;
      float bias = gib[col];
#pragma unroll
      for (int reg = 0; reg < 16; ++reg){
        int row = (reg & 3) + 8*(reg >> 2) + 4*(l >> 5);
        int it2 = row >> 4, q2 = row & 15;
        gi[((size_t)((r0 + q2)*64 + t0 + it2))*768 + col] = acc[reg] + bias;
      }
    }
  }
}

// ------------------------------------------------------------------ K3: GRU
// r20: 1024 threads = 16 waves x 3 col-tiles (halves per-wave issue on the
// sequential chain; elementwise 4 dims/thread). Same math/barriers as r18.
__global__ __launch_bounds__(1024) void k3_gru(
    const _Float16* __restrict__ WHH, const float* __restrict__ bhh,
    const float* __restrict__ gi, const float* __restrict__ h0,
    float* __restrict__ hs)
{
  const int rb = blockIdx.x;
  const int row0 = rb * 16;
  const int tid = threadIdx.x;
  const int w = tid >> 6, lg = (tid >> 4) & 3, li = tid & 15;

  extern __shared__ char smem3[];
  _Float16* hf16 = (_Float16*)smem3;
  float* hf32 = (float*)(smem3 + 8448);
  float* gh   = (float*)(smem3 + 8448 + 16640);
  float* bhs  = (float*)(smem3 + 8448 + 16640 + 49664);

  for (int idx = tid; idx < 768; idx += 1024) bhs[idx] = bhh[idx];
  for (int idx = tid; idx < 4096; idx += 1024){
    int r = idx >> 8, d = idx & 255;
    float v = h0[(size_t)(row0 + r)*256 + d];
    hf32[r*260 + d] = v;
    hf16[r*264 + d] = (_Float16)v;
  }
  __syncthreads();

  const int er = tid >> 6;            // elementwise row 0..15
  const int dd = (tid & 63) * 4;      // elementwise dim base (4 dims)

  for (int t = 0; t < 64; ++t){
    const float* gp = gi + ((size_t)(row0 + er)*64 + t)*768 + dd;
    f32x4 gr = *(const f32x4*)(gp);
    f32x4 gz = *(const f32x4*)(gp + 256);
    f32x4 gn = *(const f32x4*)(gp + 512);
    f16x8 a[8];
#pragma unroll
    for (int kk = 0; kk < 8; ++kk)
      a[kk] = *(const f16x8*)(hf16 + li*264 + kk*32 + lg*8);
    f32x4 acc[3];
#pragma unroll
    for (int c = 0; c < 3; ++c) acc[c] = 0.f;
#pragma unroll
    for (int c = 0; c < 3; ++c){
      const _Float16* bp = WHH + (size_t)(w*48 + c*16 + li)*256 + lg*8;
#pragma unroll
      for (int kk = 0; kk < 8; ++kk)
        acc[c] = mfma16(a[kk], *(const f16x8*)(bp + kk*32), acc[c]);
    }
#pragma unroll
    for (int c = 0; c < 3; ++c){
      int col = w*48 + c*16 + li;
#pragma unroll
      for (int j = 0; j < 4; ++j)
        gh[(4*lg + j)*776 + col] = acc[c][j];
    }
    __syncthreads();
    {
      float* hp32 = hf32 + er*260 + dd;
      float* hsp  = hs + ((size_t)(rb*64 + t)*16 + er)*256 + dd;
      f32x4 xr = *(const f32x4*)(gh + er*776 +       dd);
      f32x4 xz = *(const f32x4*)(gh + er*776 + 256 + dd);
      f32x4 xn = *(const f32x4*)(gh + er*776 + 512 + dd);
      f32x4 hold = *(const f32x4*)(hp32);
      f32x4 hout;
      f16x4 hv4;
#pragma unroll
      for (int e = 0; e < 4; ++e){
        int d = dd + e;
        float rr_ = 1.f/(1.f + __expf(-(gr[e] + xr[e] + bhs[d])));
        float zz  = 1.f/(1.f + __expf(-(gz[e] + xz[e] + bhs[256 + d])));
        float pre = gn[e] + rr_*(xn[e] + bhs[512 + d]);
        float nn  = 1.f - 2.f/(1.f + __expf(2.f*pre));
        float hv = (1.f - zz)*nn + zz*hold[e];
        hout[e] = hv;
        hv4[e] = (_Float16)hv;
      }
      *(f32x4*)(hp32) = hout;
      *(f32x4*)(hsp)  = hout;
      *(f16x4*)(hf16 + er*264 + dd) = hv4;
    }
    __syncthreads();
  }
}

// ------------------------------------------------------------------ K4: q out
__global__ __launch_bounds__(256) void k4_q(
    const _Float16* __restrict__ FC3T, const float* __restrict__ fc3b,
    const float* __restrict__ em, const float* __restrict__ hs, float* __restrict__ qo)
{
  const int tid = threadIdx.x;
  const int w = tid >> 6, lg = (tid >> 4) & 3, li = tid & 15;
  const int rb = blockIdx.x*64 + 16*w;
  f32x4 acc[2];
#pragma unroll
  for (int c = 0; c < 2; ++c) acc[c] = 0.f;
  for (int kk = 0; kk < 8; ++kk){
    const float* ap = hs + (size_t)(rb + li)*256 + kk*32 + lg*8;
    f32x4 v0 = *(const f32x4*)ap, v1 = *(const f32x4*)(ap + 4);
    f16x8 A;
#pragma unroll
    for (int e = 0; e < 4; ++e){ A[e] = (_Float16)v0[e]; A[e+4] = (_Float16)v1[e]; }
#pragma unroll
    for (int c = 0; c < 2; ++c){
      f16x8 B = *(const f16x8*)(FC3T + (size_t)(16*c + li)*256 + kk*32 + lg*8);
      acc[c] = mfma16(A, B, acc[c]);
    }
  }
#pragma unroll
  for (int c = 0; c < 2; ++c){
    int col = 16*c + li;
    float bias = fc3b[col];
#pragma unroll
    for (int j = 0; j < 4; ++j){
      int row = rb + 4*lg + j;
      float am = em[(size_t)(row >> 4)*64 + (row & 15)];
      qo[(size_t)row*32 + col] = (acc[c][j] + bias)*(1.f - am);
    }
  }
}

// --------------------------------------------------------------------- launch
extern "C" void kernel_launch(void* const* d_in, const int* in_sizes, int n_in,
                              void* d_out, int out_size, void* d_ws, size_t ws_size,
                              hipStream_t stream)
{
  constexpr size_t OFF_FC1T   = 0;
  constexpr size_t OFF_MSG1T  = 49152;
  constexpr size_t OFF_AINT   = 98304;
  constexpr size_t OFF_LINT   = 491520;
  constexpr size_t OFF_AOUTT  = 884736;
  constexpr size_t OFF_LOUTT  = 1015808;
  constexpr size_t OFF_GMINT  = 1146880;
  constexpr size_t OFF_GMOUTT = 1540096;
  constexpr size_t OFF_FC2T   = 1671168;
  constexpr size_t OFF_GIHT   = 1933312;
  constexpr size_t OFF_GHHT   = 2326528;
  constexpr size_t OFF_FC3T   = 2719744;
  constexpr size_t OFF_G1T    = 2736128;
  constexpr size_t OFF_GINT   = 2834432;
  constexpr size_t OFF_WVEFF  = 3620864;
  constexpr size_t OFF_BEFF   = 3637248;
  constexpr size_t OFF_GATE   = 3637504;
  constexpr size_t OFF_X2     = 3768576;
  constexpr size_t OFF_X2M    = 37323008;
  constexpr size_t OFF_GI     = 70877440;
  constexpr size_t NEED       = 171540736;
  if (ws_size < NEED) return;

  char* ws = (char*)d_ws;
  const float* ent = (const float*)d_in[0];
  const float* om  = (const float*)d_in[1];
  const float* em  = (const float*)d_in[2];

  WJobs jb{};
  int nj = 0;
  auto addj = [&](int src_idx, size_t off, int K, int N, int m){
    jb.src[nj] = (const float*)d_in[src_idx]; jb.off[nj] = (unsigned)off;
    jb.K[nj] = K; jb.N[nj] = N; jb.mode[nj] = m; ++nj;
  };
  addj(4,  OFF_FC1T,   96, 256, 0);
  addj(17, OFF_MSG1T,  96, 256, 0);
  addj(6,  OFF_AINT,  256, 768, 0);
  addj(19, OFF_LINT,  256, 768, 0);
  addj(7,  OFF_AOUTT, 256, 256, 0);
  addj(20, OFF_LOUTT, 256, 256, 0);
  addj(22, OFF_GMINT, 256, 768, 0);
  addj(23, OFF_GMOUTT,256, 256, 0);
  addj(9,  OFF_FC2T,  512, 256, 0);
  addj(11, OFF_GIHT,  256, 768, 0);
  addj(12, OFF_GHHT,  256, 768, 0);
  addj(15, OFF_FC3T,  256,  32, 0);
  addj(28, OFF_G1T,    96, 256, 1);
  addj(25, OFF_GINT,  256, 768, 1);
  k0_conv<<<dim3(96, nj), 256, 0, stream>>>(jb, ws);

  k0w_gate<<<1, 256, 0, stream>>>(
      (const float*)d_in[26], (const float*)d_in[30],
      (const float*)d_in[27], (const float*)d_in[25],
      (_Float16*)(ws + OFF_WVEFF), (float*)(ws + OFF_BEFF));

  constexpr int SMB2 = 76032, SMG = 149248, SMK2 = 131200, SM3 = 77824;
  (void)hipFuncSetAttribute(reinterpret_cast<const void*>(&k1_b2),
                            hipFuncAttributeMaxDynamicSharedMemorySize, SMB2);
  (void)hipFuncSetAttribute(reinterpret_cast<const void*>(&k1_gate),
                            hipFuncAttributeMaxDynamicSharedMemorySize, SMG);
  (void)hipFuncSetAttribute(reinterpret_cast<const void*>(&k2_global),
                            hipFuncAttributeMaxDynamicSharedMemorySize, SMK2);
  (void)hipFuncSetAttribute(reinterpret_cast<const void*>(&k3_gru),
                            hipFuncAttributeMaxDynamicSharedMemorySize, SM3);

  float* qout = (float*)d_out;
  float* hsout = qout + 1048576;
  float* gout = qout + 9437184;

  k1_b2<<<4096, 512, SMB2, stream>>>(ent, om, em,
      (const _Float16*)(ws + OFF_FC1T),  (const float*)d_in[5],
      (const _Float16*)(ws + OFF_AINT),
      (const _Float16*)(ws + OFF_AOUTT), (const float*)d_in[8],
      (float*)(ws + OFF_X2),
      (const _Float16*)(ws + OFF_MSG1T), (const float*)d_in[18],
      (const _Float16*)(ws + OFF_LINT),
      (const _Float16*)(ws + OFF_LOUTT), (const float*)d_in[21],
      (float*)(ws + OFF_X2M));

  k1_gate<<<2048, 512, SMG, stream>>>(ent, om, em,
      (const _Float16*)(ws + OFF_G1T),   (const float*)d_in[29],
      (const _Float16*)(ws + OFF_GINT),
      (const _Float16*)(ws + OFF_WVEFF),
      (const float*)(ws + OFF_BEFF), (const float*)d_in[31],
      gout, (float*)(ws + OFF_GATE));

  k2_global<<<1024, 256, SMK2, stream>>>(em,
      (const float*)(ws + OFF_X2), (const float*)(ws + OFF_X2M),
      (const float*)(ws + OFF_GATE),
      (const _Float16*)(ws + OFF_GMINT), (const _Float16*)(ws + OFF_GMOUTT), (const float*)d_in[24],
      (const _Float16*)(ws + OFF_FC2T), (const float*)d_in[10],
      (const _Float16*)(ws + OFF_GIHT), (const float*)d_in[13],
      (float*)(ws + OFF_GI));

  k3_gru<<<32, 1024, SM3, stream>>>(
      (const _Float16*)(ws + OFF_GHHT), (const float*)d_in[14],
      (const float*)(ws + OFF_GI), (const float*)d_in[3], hsout);

  k4_q<<<512, 256, 0, stream>>>(
      (const _Float16*)(ws + OFF_FC3T), (const float*)d_in[16],
      em, hsout, qout);
}

// Round 21
// 1259.743 us; speedup vs baseline: 1.0297x; 1.0297x over previous
//
#include <hip/hip_runtime.h>

// EntityAttentionRNNMsgAgent — fused MI355X implementation.
// r21 = r19 (fused k1_all restored after r20's split regressed via
// serialization) + k3: gi double-buffered register prefetch — issue step
// t+1's gi loads before step t's MFMA so the ~900cy HBM latency hides under
// compute instead of serializing the 64-step chain. k3 otherwise the
// r18-verified 512-thread version. All else byte-identical to r19 (1143.6us).

#define DEV __device__ __forceinline__

typedef _Float16 f16x8 __attribute__((ext_vector_type(8)));
typedef _Float16 f16x4 __attribute__((ext_vector_type(4)));
typedef float    f32x4 __attribute__((ext_vector_type(4)));
typedef float    f32x16 __attribute__((ext_vector_type(16)));

DEV f32x4 mfma16(f16x8 a, f16x8 b, f32x4 c){
  return __builtin_amdgcn_mfma_f32_16x16x32_f16(a, b, c, 0, 0, 0);
}
DEV f32x16 mfma32(f16x8 a, f16x8 b, f32x16 c){
  return __builtin_amdgcn_mfma_f32_32x32x16_f16(a, b, c, 0, 0, 0);
}

// A/B fragment pair for optional split-precision (MODE=1: value = hi + lo)
template<int MODE> struct AB {
  f16x8 hi, lo;
  DEV void mf(const AB& b, f32x4& c) const {
    if constexpr (MODE){
      c = mfma16(lo, b.hi, c);
      c = mfma16(hi, b.lo, c);
    }
    c = mfma16(hi, b.hi, c);
  }
};

template<int MODE> DEV AB<MODE> ldW(const _Float16* p, int losz){
  AB<MODE> r; r.hi = *(const f16x8*)p;
  if constexpr (MODE) r.lo = *(const f16x8*)(p + losz);
  return r;
}
template<int MODE> DEV AB<MODE> ldL(const _Float16* ph, const _Float16* pl){
  AB<MODE> r; r.hi = *(const f16x8*)ph;
  if constexpr (MODE) r.lo = *(const f16x8*)pl;
  return r;
}
template<int MODE> DEV AB<MODE> ldF(const float* p){
  AB<MODE> r;
  f32x4 v0 = *(const f32x4*)p, v1 = *(const f32x4*)(p + 4);
#pragma unroll
  for (int i = 0; i < 4; ++i){
    float a = v0[i], b = v1[i];
    _Float16 ah = (_Float16)a, bh = (_Float16)b;
    r.hi[i] = ah; r.hi[i+4] = bh;
    if constexpr (MODE){
      r.lo[i]   = (_Float16)(a - (float)ah);
      r.lo[i+4] = (_Float16)(b - (float)bh);
    }
  }
  return r;
}
template<int MODE> DEV void stL(_Float16* ph, _Float16* pl, int idx, float v){
  _Float16 h = (_Float16)v;
  ph[idx] = h;
  if constexpr (MODE) pl[idx] = (_Float16)(v - (float)h);
}

// ---------------------------------------------------------------- K0: weights
struct WJobs {
  const float* src[15];
  unsigned off[15];
  int K[15], N[15], mode[15];
};

__global__ __launch_bounds__(256) void k0_conv(WJobs jb, char* ws){
  const int job = blockIdx.y;
  const int K = jb.K[job], N = jb.N[job];
  const int total = K * N;
  _Float16* dh = (_Float16*)(ws + jb.off[job]);
  const float* src = jb.src[job];
  const int m = jb.mode[job];
  for (int idx = blockIdx.x*256 + threadIdx.x; idx < total; idx += gridDim.x*256){
    int n = idx / K, k = idx - n*K;
    float v = src[(size_t)k*N + n];
    _Float16 h = (_Float16)v;
    dh[idx] = h;
    if (m) dh[total + idx] = (_Float16)(v - (float)h);
  }
}

// ------------------------------------------------- K0w: gate-tail precompute
__global__ __launch_bounds__(256) void k0w_gate(
    const float* __restrict__ Wout, const float* __restrict__ Wg2,
    const float* __restrict__ bo,   const float* __restrict__ Win,
    _Float16* __restrict__ wveff, float* __restrict__ beff)
{
  __shared__ float weff_s[256*2];
  const int tid = threadIdx.x;
  {
    float a0 = 0.f, a1 = 0.f;
    const float* wr = Wout + (size_t)tid*256;
    for (int f = 0; f < 256; ++f){ float x = wr[f]; a0 += x*Wg2[2*f]; a1 += x*Wg2[2*f+1]; }
    weff_s[tid*2] = a0; weff_s[tid*2+1] = a1;
  }
  if (tid < 2){
    float s = 0.f;
    for (int f = 0; f < 256; ++f) s += bo[f]*Wg2[2*f + tid];
    beff[tid] = s;
  }
  __syncthreads();
  {
    const int j = tid;
    for (int n = 0; n < 16; ++n){
      float v = 0.f;
      if (n < 8){
        int h = n >> 1, c = n & 1;
        const float* wr = Win + (size_t)j*768 + 512 + h*64;
        const float* we = weff_s + (h*64)*2 + c;
        for (int d = 0; d < 64; ++d) v += wr[d]*we[2*d];
      }
      _Float16 hi = (_Float16)v;
      wveff[n*256 + j] = hi;
      wveff[16*256 + n*256 + j] = (_Float16)(v - (float)hi);
    }
  }
}

// -------------------------------------------- K1 fused: branch2 + gate roles
__global__ __launch_bounds__(512) void k1_all(
    const float* __restrict__ ent, const float* __restrict__ om, const float* __restrict__ em,
    const _Float16* __restrict__ W1a, const float* __restrict__ b1a,
    const _Float16* __restrict__ WINa,
    const _Float16* __restrict__ WOUTa, const float* __restrict__ boa,
    float* __restrict__ x2outa,
    const _Float16* __restrict__ W1b, const float* __restrict__ b1b,
    const _Float16* __restrict__ WINb,
    const _Float16* __restrict__ WOUTb, const float* __restrict__ bob,
    float* __restrict__ x2outb,
    const _Float16* __restrict__ W1g, const float* __restrict__ b1g,
    const _Float16* __restrict__ WINg,
    const _Float16* __restrict__ WVEFF,
    const float* __restrict__ beff, const float* __restrict__ gb2,
    float* __restrict__ og, float* __restrict__ gate)
{
  const int tid = threadIdx.x;
  const int w = tid >> 6, lg = (tid >> 4) & 3, li = tid & 15;
  extern __shared__ char smem[];

  if (blockIdx.x < 2048){
    // ============================ branch2 role ============================
    const int br = blockIdx.x >> 10;
    const int p  = blockIdx.x & 1023;
    const int bb2[2] = { 2*p, 2*p + 1 };
    const _Float16* W1   = br ? W1b   : W1a;
    const float*    b1   = br ? b1b   : b1a;
    const _Float16* WIN  = br ? WINb  : WINa;
    const _Float16* WOUT = br ? WOUTb : WOUTa;
    const float*    bo   = br ? bob   : boa;
    float*          x2out= br ? x2outb: x2outa;

    const int wi = w & 3, ih = w >> 2;
    const int l = tid & 63;
    const int r32 = l & 31, kh = (l >> 5)*8;

    _Float16* x1   = (_Float16*)smem;
    _Float16* Ks   = (_Float16*)(smem + 67584);
    _Float16* Vs   = (_Float16*)(smem + 86016);
    _Float16* Qful = (_Float16*)(smem + 104448);
    float*    lgs  = (float*)(smem + 121344);
    _Float16* Ps   = (_Float16*)(smem + 130560);
    _Float16* outp = (_Float16*)(smem + 135168);

    { // phase 1: x1 = relu(ent @ W1 + b1) via 32x32x16
      const int b = bb2[ih];
      _Float16* x1p = x1 + ih*16896;
      const int mt = wi & 1, ntb = (wi >> 1)*4;
      f32x16 acc0 = 0.f, acc1 = 0.f, acc2 = 0.f, acc3 = 0.f;
#pragma unroll
      for (int kk = 0; kk < 6; ++kk){
        AB<0> a = ldF<0>(ent + ((size_t)b*64 + mt*32 + r32)*96 + kk*16 + kh);
        f16x8 B0 = *(const f16x8*)(W1 + (size_t)((ntb + 0)*32 + r32)*96 + kk*16 + kh);
        f16x8 B1 = *(const f16x8*)(W1 + (size_t)((ntb + 1)*32 + r32)*96 + kk*16 + kh);
        f16x8 B2 = *(const f16x8*)(W1 + (size_t)((ntb + 2)*32 + r32)*96 + kk*16 + kh);
        f16x8 B3 = *(const f16x8*)(W1 + (size_t)((ntb + 3)*32 + r32)*96 + kk*16 + kh);
        acc0 = mfma32(a.hi, B0, acc0);
        acc1 = mfma32(a.hi, B1, acc1);
        acc2 = mfma32(a.hi, B2, acc2);
        acc3 = mfma32(a.hi, B3, acc3);
      }
#pragma unroll
      for (int s = 0; s < 4; ++s){
        const f32x16& ac = (s == 0) ? acc0 : (s == 1) ? acc1 : (s == 2) ? acc2 : acc3;
        int col = (ntb + s)*32 + r32;
        float bias = b1[col];
#pragma unroll
        for (int reg = 0; reg < 16; ++reg){
          int row = (reg & 3) + 8*(reg >> 2) + 4*(l >> 5);
          x1p[(mt*32 + row)*264 + col] = (_Float16)fmaxf(ac[reg] + bias, 0.f);
        }
      }
    }
    __syncthreads();

    { // Qfull = x1[rows 0..15, both items stacked M=32] @ Wq; wave -> n-tile w
      f32x16 acc = 0.f;
      const int itq = r32 >> 4, qr = r32 & 15;
      for (int kk = 0; kk < 16; ++kk){
        f16x8 A = *(const f16x8*)(x1 + itq*16896 + qr*264 + kk*16 + kh);
        f16x8 B = *(const f16x8*)(WIN + (size_t)(w*32 + r32)*256 + kk*16 + kh);
        acc = mfma32(A, B, acc);
      }
#pragma unroll
      for (int reg = 0; reg < 16; ++reg){
        int row = (reg & 3) + 8*(reg >> 2) + 4*(l >> 5);
        Qful[(row >> 4)*4224 + (row & 15)*264 + w*32 + r32] = (_Float16)acc[reg];
      }
    }
    __syncthreads();

    for (int h = 0; h < 4; ++h){
      if (w < 4){
        const int kt = w >> 1, dt = w & 1;
        f32x16 acc0 = 0.f, acc1 = 0.f;
        for (int kk = 0; kk < 16; ++kk){
          int ao = (kt*32 + r32)*264 + kk*16 + kh;
          f16x8 A0 = *(const f16x8*)(x1 + ao);
          f16x8 A1 = *(const f16x8*)(x1 + 16896 + ao);
          f16x8 B = *(const f16x8*)(WIN + (size_t)(256 + 64*h + dt*32 + r32)*256 + kk*16 + kh);
          acc0 = mfma32(A0, B, acc0);
          acc1 = mfma32(A1, B, acc1);
        }
#pragma unroll
        for (int reg = 0; reg < 16; ++reg){
          int row = (reg & 3) + 8*(reg >> 2) + 4*(l >> 5);
          Ks[(kt*32 + row)*72 + dt*32 + r32]        = (_Float16)acc0[reg];
          Ks[4608 + (kt*32 + row)*72 + dt*32 + r32] = (_Float16)acc1[reg];
        }
      } else {
        const int wv = w - 4;
        const int kt = wv >> 1, dt = wv & 1;
        f32x16 acc0 = 0.f, acc1 = 0.f;
        for (int kk = 0; kk < 16; ++kk){
          int ao = (kt*32 + r32)*264 + kk*16 + kh;
          f16x8 A0 = *(const f16x8*)(x1 + ao);
          f16x8 A1 = *(const f16x8*)(x1 + 16896 + ao);
          f16x8 B = *(const f16x8*)(WIN + (size_t)(512 + 64*h + dt*32 + r32)*256 + kk*16 + kh);
          acc0 = mfma32(A0, B, acc0);
          acc1 = mfma32(A1, B, acc1);
        }
#pragma unroll
        for (int rr = 0; rr < 4; ++rr){
          f16x4 p0, p1;
#pragma unroll
          for (int q4 = 0; q4 < 4; ++q4){
            p0[q4] = (_Float16)acc0[rr*4 + q4];
            p1[q4] = (_Float16)acc1[rr*4 + q4];
          }
          int key = kt*32 + rr*8 + 4*(l >> 5);
          *(f16x4*)(Vs + (dt*32 + r32)*72 + key)        = p0;
          *(f16x4*)(Vs + 4608 + (dt*32 + r32)*72 + key) = p1;
        }
      }
      __syncthreads();
      { // logits: A from Qful
        const int b = bb2[ih];
        f32x4 acc = 0.f;
#pragma unroll
        for (int kk = 0; kk < 2; ++kk){
          f16x8 A = *(const f16x8*)(Qful + ih*4224 + li*264 + 64*h + kk*32 + lg*8);
          f16x8 B = *(const f16x8*)(Ks + ih*4608 + (16*wi + li)*72 + kk*32 + lg*8);
          acc = mfma16(A, B, acc);
        }
#pragma unroll
        for (int j = 0; j < 4; ++j){
          int q = 4*lg + j, key = 16*wi + li;
          float v = acc[j] * 0.125f;
          float m = om[((size_t)b*64 + q)*64 + key];
          if (m > 0.f) v = -1e9f;
          lgs[ih*1152 + q*72 + key] = v;
        }
      }
      __syncthreads();
      { // softmax
        const int it = tid >> 8, q = (tid >> 4) & 15, i16 = tid & 15;
        const int b = bb2[it];
        float pv[4], mx = -3e38f;
#pragma unroll
        for (int u = 0; u < 4; ++u){ pv[u] = lgs[it*1152 + q*72 + i16 + 16*u]; mx = fmaxf(mx, pv[u]); }
#pragma unroll
        for (int d = 1; d < 16; d <<= 1) mx = fmaxf(mx, __shfl_xor(mx, d, 16));
        float s = 0.f;
#pragma unroll
        for (int u = 0; u < 4; ++u){ pv[u] = expf(pv[u] - mx); s += pv[u]; }
#pragma unroll
        for (int d = 1; d < 16; d <<= 1) s += __shfl_xor(s, d, 16);
#pragma unroll
        for (int u = 0; u < 4; ++u){
          int key = i16 + 16*u;
          float m = om[((size_t)b*64 + q)*64 + key];
          Ps[it*1152 + q*72 + key] = (_Float16)((pv[u]/s)*(1.f - m));
        }
      }
      __syncthreads();
      { // out_h = P @ V_h; outp stored f16
        f32x4 acc = 0.f;
#pragma unroll
        for (int kk = 0; kk < 2; ++kk){
          f16x8 A = *(const f16x8*)(Ps + ih*1152 + li*72 + kk*32 + lg*8);
          f16x8 B = *(const f16x8*)(Vs + ih*4608 + (16*wi + li)*72 + kk*32 + lg*8);
          acc = mfma16(A, B, acc);
        }
#pragma unroll
        for (int j = 0; j < 4; ++j)
          outp[ih*4224 + (4*lg + j)*264 + 64*h + 16*wi + li] = (_Float16)acc[j];
      }
      __syncthreads();
    }

    { // out-proj via 32x32, stacked M=32; wave -> n-tile w
      f32x16 acc = 0.f;
      const int ito = r32 >> 4, qr = r32 & 15;
      for (int kk = 0; kk < 16; ++kk){
        f16x8 A = *(const f16x8*)(outp + ito*4224 + qr*264 + kk*16 + kh);
        f16x8 B = *(const f16x8*)(WOUT + (size_t)(w*32 + r32)*256 + kk*16 + kh);
        acc = mfma32(A, B, acc);
      }
      int col = w*32 + r32;
      float bias = bo[col];
#pragma unroll
      for (int reg = 0; reg < 16; ++reg){
        int row = (reg & 3) + 8*(reg >> 2) + 4*(l >> 5);
        int it2 = row >> 4, q2 = row & 15;
        const int b = bb2[it2];
        float v = (acc[reg] + bias) * (1.f - em[(size_t)b*64 + q2]);
        x2out[((size_t)b*16 + q2)*256 + col] = v;
      }
    }
    return;
  }

  // ============================== gate role ==============================
  {
    constexpr int W1SZ = 96*256, WINSZ = 256*768, WVSZ = 16*256;
    const int b = blockIdx.x - 2048;
    const int l = tid & 63;
    const int r32 = l & 31, kh = (l >> 5)*8;

    char* sp = smem;
    _Float16* x1h = (_Float16*)sp; sp += 64*264*2;
    _Float16* x1l = (_Float16*)sp; sp += 64*264*2;
    _Float16* Kh  = (_Float16*)sp; sp += 64*72*2;
    _Float16* Kl  = (_Float16*)sp; sp += 64*72*2;
    _Float16* Qh  = (_Float16*)sp; sp += 16*264*2;
    _Float16* Ql  = (_Float16*)sp; sp += 16*264*2;
    float*    lgs = (float*)sp;    sp += 16*72*4;
    float*    Ps  = (float*)sp;    sp += 16*66*4;
    float*    v2s = (float*)sp;    sp += 64*18*4;
    float*  ogacc = (float*)sp;    sp += 32*4;
    float*  Kpart = (float*)sp;    sp += 8192*4;

    { // phase 1: x1 = relu(ent @ W1g + b1g), 32x32 split-2
      const int mt = w & 1, ntb = (w >> 1)*2;
      f32x16 acc0 = 0.f, acc1 = 0.f;
#pragma unroll
      for (int kk = 0; kk < 6; ++kk){
        AB<1> a = ldF<1>(ent + ((size_t)b*64 + mt*32 + r32)*96 + kk*16 + kh);
#pragma unroll
        for (int s = 0; s < 2; ++s){
          const _Float16* bp = W1g + (size_t)((ntb + s)*32 + r32)*96 + kk*16 + kh;
          f16x8 Bh = *(const f16x8*)bp;
          f16x8 Bl = *(const f16x8*)(bp + W1SZ);
          f32x16& ac = s ? acc1 : acc0;
          ac = mfma32(a.lo, Bh, ac);
          ac = mfma32(a.hi, Bl, ac);
          ac = mfma32(a.hi, Bh, ac);
        }
      }
#pragma unroll
      for (int s = 0; s < 2; ++s){
        const f32x16& ac = s ? acc1 : acc0;
        int col = (ntb + s)*32 + r32;
        float bias = b1g[col];
#pragma unroll
        for (int reg = 0; reg < 16; ++reg){
          int row = (reg & 3) + 8*(reg >> 2) + 4*(l >> 5);
          stL<1>(x1h, x1l, (mt*32 + row)*264 + col, fmaxf(ac[reg] + bias, 0.f));
        }
      }
    }
    if (tid < 32) ogacc[tid] = 0.f;
    __syncthreads();

    { // phase 2: Qfull (16x16 split-2), v2
#pragma unroll
      for (int s = 0; s < 2; ++s){
        int nt = w + s*8;
        f32x4 acc = 0.f;
        for (int kk = 0; kk < 8; ++kk){
          int ao = li*264 + kk*32 + lg*8;
          AB<1> a = ldL<1>(x1h + ao, x1l + ao);
          AB<1> bb = ldW<1>(WINg + (size_t)(nt*16 + li)*256 + kk*32 + lg*8, WINSZ);
          a.mf(bb, acc);
        }
#pragma unroll
        for (int j = 0; j < 4; ++j)
          stL<1>(Qh, Ql, (4*lg + j)*264 + nt*16 + li, acc[j]);
      }
      if (w < 4){
        f32x4 acc = 0.f;
        for (int kk = 0; kk < 8; ++kk){
          int ao = (w*16 + li)*264 + kk*32 + lg*8;
          AB<1> a = ldL<1>(x1h + ao, x1l + ao);
          AB<1> bb = ldW<1>(WVEFF + (size_t)li*256 + kk*32 + lg*8, WVSZ);
          a.mf(bb, acc);
        }
#pragma unroll
        for (int j = 0; j < 4; ++j)
          v2s[(w*16 + 4*lg + j)*18 + li] = acc[j];
      }
    }
    __syncthreads();

    for (int h = 0; h < 4; ++h){
      { // K_h partials: 32x32 split-2, tiles x k-halves across 8 waves
        const int t = w & 3, kt = t >> 1, dt = t & 1, khalf = w >> 2;
        f32x16 acc = 0.f;
#pragma unroll
        for (int k8 = 0; k8 < 8; ++k8){
          int ko = (khalf*8 + k8)*16 + kh;
          int ao = (kt*32 + r32)*264 + ko;
          f16x8 ah = *(const f16x8*)(x1h + ao);
          f16x8 al = *(const f16x8*)(x1l + ao);
          const _Float16* bp = WINg + (size_t)(256 + h*64 + dt*32 + r32)*256 + ko;
          f16x8 Bh = *(const f16x8*)bp;
          f16x8 Bl = *(const f16x8*)(bp + WINSZ);
          acc = mfma32(al, Bh, acc);
          acc = mfma32(ah, Bl, acc);
          acc = mfma32(ah, Bh, acc);
        }
#pragma unroll
        for (int reg = 0; reg < 16; ++reg){
          int row = (reg & 3) + 8*(reg >> 2) + 4*(l >> 5);
          Kpart[((khalf*4 + t)*32 + row)*32 + r32] = acc[reg];
        }
      }
      __syncthreads();
      { // reduce k-halves -> Kh/Kl
        for (int e = tid; e < 4096; e += 512){
          float s2 = Kpart[e] + Kpart[4096 + e];
          int t2 = e >> 10, idx = e & 1023, row = idx >> 5, col = idx & 31;
          stL<1>(Kh, Kl, ((t2 >> 1)*32 + row)*72 + (t2 & 1)*32 + col, s2);
        }
      }
      __syncthreads();
      if (w < 4){ // logits
        f32x4 acc = 0.f;
#pragma unroll
        for (int kk = 0; kk < 2; ++kk){
          int ao = li*264 + h*64 + kk*32 + lg*8;
          AB<1> a = ldL<1>(Qh + ao, Ql + ao);
          int bo_ = (16*w + li)*72 + kk*32 + lg*8;
          AB<1> bb = ldL<1>(Kh + bo_, Kl + bo_);
          a.mf(bb, acc);
        }
#pragma unroll
        for (int j = 0; j < 4; ++j){
          int q = 4*lg + j, key = 16*w + li;
          float v = acc[j] * 0.125f;
          float m = om[((size_t)b*64 + q)*64 + key];
          if (m > 0.f) v = -1e9f;
          lgs[q*72 + key] = v;
        }
      }
      __syncthreads();
      if (tid < 256){ // softmax
        int q = tid >> 4, i16 = tid & 15;
        float pv[4], mx = -3e38f;
#pragma unroll
        for (int u = 0; u < 4; ++u){ pv[u] = lgs[q*72 + i16 + 16*u]; mx = fmaxf(mx, pv[u]); }
#pragma unroll
        for (int d = 1; d < 16; d <<= 1) mx = fmaxf(mx, __shfl_xor(mx, d, 16));
        float s = 0.f;
#pragma unroll
        for (int u = 0; u < 4; ++u){ pv[u] = expf(pv[u] - mx); s += pv[u]; }
#pragma unroll
        for (int d = 1; d < 16; d <<= 1) s += __shfl_xor(s, d, 16);
#pragma unroll
        for (int u = 0; u < 4; ++u){
          int key = i16 + 16*u;
          float m = om[((size_t)b*64 + q)*64 + key];
          Ps[q*66 + key] = (pv[u]/s)*(1.f - m);
        }
      }
      __syncthreads();
      if (tid < 256){ // og += P_h . v2_h
        int q = tid >> 4, l16 = tid & 15;
        float a0 = 0.f, a1 = 0.f;
#pragma unroll
        for (int u = 0; u < 4; ++u){
          int k = l16 + 16*u;
          float p2 = Ps[q*66 + k];
          a0 += p2 * v2s[k*18 + h*2];
          a1 += p2 * v2s[k*18 + h*2 + 1];
        }
#pragma unroll
        for (int d = 1; d < 16; d <<= 1){ a0 += __shfl_xor(a0, d, 16); a1 += __shfl_xor(a1, d, 16); }
        if (l16 == 0){ ogacc[q*2] += a0; ogacc[q*2 + 1] += a1; }
      }
      __syncthreads();
    }
    if (tid < 16){
      int q = tid;
      float am = em[(size_t)b*64 + q];
      float g0 = (1.f - am)*(ogacc[2*q]     + beff[0]) + gb2[0];
      float g1 = (1.f - am)*(ogacc[2*q + 1] + beff[1]) + gb2[1];
      og[((size_t)b*16 + q)*2]     = g0;
      og[((size_t)b*16 + q)*2 + 1] = g1;
      gate[(size_t)b*16 + q] = (g1 > g0) ? 1.f : 0.f;
    }
  }
}

// ------------------- K2: gate, global attention, fc2, gi — 2 items/block
__global__ __launch_bounds__(256) void k2_global(
    const float* __restrict__ em,
    const float* __restrict__ x2, const float* __restrict__ x2m,
    const float* __restrict__ gate,
    const _Float16* __restrict__ GMIN, const _Float16* __restrict__ GMOUT, const float* __restrict__ gob,
    const _Float16* __restrict__ FC2T, const float* __restrict__ fc2b,
    const _Float16* __restrict__ GIHT, const float* __restrict__ gib,
    float* __restrict__ gi)
{
  const int p = blockIdx.x;
  const int tid = threadIdx.x;
  const int w = tid >> 6, lg = (tid >> 4) & 3, li = tid & 15;
  const int l = tid & 63;
  const int r32 = l & 31, kh = (l >> 5)*8;

  extern __shared__ char smem[];
  float*    gate_s = (float*)smem;
  _Float16* gm_s   = (_Float16*)(smem + 128);
  float*    lg2    = (float*)(smem + 17024);
  _Float16* P2     = (_Float16*)(smem + 20096);
  _Float16* outp   = (_Float16*)(smem + 22656);
  _Float16* x3_s   = (_Float16*)(smem + 39552);
  _Float16* Vtall  = (_Float16*)(smem + 56448);
  _Float16* Qall   = (_Float16*)(smem + 97408);
  _Float16* Kall   = (_Float16*)(smem + 114304);
  _Float16* cat_s  = (_Float16*)(smem + 97408);   // overlay

  if (tid < 32){
    int it = tid >> 4, q = tid & 15;
    gate_s[it*16 + q] = gate[(size_t)(2*p + it)*16 + q];
  }
  __syncthreads();
#pragma unroll
  for (int it = 0; it < 2; ++it){
    const int b = 2*p + it;
    for (int idx = tid; idx < 4096; idx += 256){
      int q = idx >> 8, d = idx & 255;
      gm_s[it*4224 + q*264 + d] = (_Float16)(x2m[((size_t)b*16 + q)*256 + d] * gate_s[it*16 + q]);
    }
  }
  for (int idx = tid; idx < 10240; idx += 256) ((unsigned*)Vtall)[idx] = 0u;
  for (int idx = tid; idx < 2*16*40; idx += 256) P2[idx] = (_Float16)0.f;
  __syncthreads();

  { // QKVall = gm_stacked(32x256) @ GMIN(768x256); wave -> n-tiles {6w..6w+5}
    const int itq = r32 >> 4, qr = r32 & 15;
#pragma unroll
    for (int s = 0; s < 6; ++s){
      int nt = 6*w + s;
      f32x16 acc = 0.f;
      for (int kk = 0; kk < 16; ++kk){
        f16x8 A = *(const f16x8*)(gm_s + itq*4224 + qr*264 + kk*16 + kh);
        f16x8 B = *(const f16x8*)(GMIN + (size_t)(nt*32 + r32)*256 + kk*16 + kh);
        acc = mfma32(A, B, acc);
      }
      int sec = nt >> 3;
      int hcol = (nt & 7)*32 + r32;
#pragma unroll
      for (int reg = 0; reg < 16; ++reg){
        int row = (reg & 3) + 8*(reg >> 2) + 4*(l >> 5);
        int it2 = row >> 4, q2 = row & 15;
        _Float16 v = (_Float16)acc[reg];
        if (sec == 0)      Qall[it2*4224 + q2*264 + hcol] = v;
        else if (sec == 1) Kall[it2*4224 + q2*264 + hcol] = v;
        else               Vtall[it2*10240 + hcol*40 + q2] = v;
      }
    }
  }
  __syncthreads();

  for (int h = 0; h < 4; ++h){
    if (w < 2){
      const int it = w, b = 2*p + it;
      f32x4 acc = 0.f;
#pragma unroll
      for (int kk = 0; kk < 2; ++kk){
        f16x8 A = *(const f16x8*)(Qall + it*4224 + li*264 + 64*h + kk*32 + lg*8);
        f16x8 B = *(const f16x8*)(Kall + it*4224 + li*264 + 64*h + kk*32 + lg*8);
        acc = mfma16(A, B, acc);
      }
      float amk = em[(size_t)b*64 + li];
#pragma unroll
      for (int j = 0; j < 4; ++j){
        int q = 4*lg + j;
        float amq = em[(size_t)b*64 + q];
        float m = 1.f - (1.f - amq)*(1.f - amk);
        float v = acc[j]*0.125f;
        if (m > 0.f) v = -1e9f;
        lg2[it*384 + q*24 + li] = v;
      }
    }
    __syncthreads();
    {
      int q = tid >> 4, key = tid & 15;
#pragma unroll
      for (int it = 0; it < 2; ++it){
        const int b = 2*p + it;
        float v = lg2[it*384 + q*24 + key];
        float mx = v;
#pragma unroll
        for (int d = 1; d < 16; d <<= 1) mx = fmaxf(mx, __shfl_xor(mx, d, 16));
        float pe = expf(v - mx);
        float s = pe;
#pragma unroll
        for (int d = 1; d < 16; d <<= 1) s += __shfl_xor(s, d, 16);
        float amq = em[(size_t)b*64 + q], amk = em[(size_t)b*64 + key];
        float m = 1.f - (1.f - amq)*(1.f - amk);
        P2[it*640 + q*40 + key] = (_Float16)((pe/s)*(1.f - m));
      }
    }
    __syncthreads();
    {
#pragma unroll
      for (int it = 0; it < 2; ++it){
        f32x4 acc = 0.f;
        f16x8 A = *(const f16x8*)(P2 + it*640 + li*40 + lg*8);
        f16x8 B = *(const f16x8*)(Vtall + it*10240 + (size_t)(64*h + 16*w + li)*40 + lg*8);
        acc = mfma16(A, B, acc);
#pragma unroll
        for (int j = 0; j < 4; ++j)
          outp[it*4224 + (4*lg + j)*264 + 64*h + 16*w + li] = (_Float16)acc[j];
      }
    }
    __syncthreads();
  }
  { // gmsg out-proj stacked M=32; also stage x2 -> cat[:,0:256]
    const int ito = r32 >> 4, qr = r32 & 15;
#pragma unroll
    for (int s = 0; s < 2; ++s){
      int nt = 2*w + s;
      f32x16 acc = 0.f;
      for (int kk = 0; kk < 16; ++kk){
        f16x8 A = *(const f16x8*)(outp + ito*4224 + qr*264 + kk*16 + kh);
        f16x8 B = *(const f16x8*)(GMOUT + (size_t)(nt*32 + r32)*256 + kk*16 + kh);
        acc = mfma32(A, B, acc);
      }
      int col = nt*32 + r32;
      float bias = gob[col];
#pragma unroll
      for (int reg = 0; reg < 16; ++reg){
        int row = (reg & 3) + 8*(reg >> 2) + 4*(l >> 5);
        int it2 = row >> 4, q2 = row & 15;
        float m = 1.f - em[(size_t)(2*p + it2)*64 + q2];
        cat_s[it2*8320 + q2*520 + 256 + col] = (_Float16)((acc[reg] + bias)*m);
      }
    }
#pragma unroll
    for (int it = 0; it < 2; ++it){
      const int b = 2*p + it;
      for (int idx = tid; idx < 4096; idx += 256){
        int q = idx >> 8, d = idx & 255;
        cat_s[it*8320 + q*520 + d] = (_Float16)(x2[((size_t)b*16 + q)*256 + d]);
      }
    }
  }
  __syncthreads();
  { // x3 = relu(cat @ fc2 + b) stacked M=32, K=512
    const int ito = r32 >> 4, qr = r32 & 15;
#pragma unroll
    for (int s = 0; s < 2; ++s){
      int nt = 2*w + s;
      f32x16 acc = 0.f;
      for (int kk = 0; kk < 32; ++kk){
        f16x8 A = *(const f16x8*)(cat_s + ito*8320 + qr*520 + kk*16 + kh);
        f16x8 B = *(const f16x8*)(FC2T + (size_t)(nt*32 + r32)*512 + kk*16 + kh);
        acc = mfma32(A, B, acc);
      }
      int col = nt*32 + r32;
      float bias = fc2b[col];
#pragma unroll
      for (int reg = 0; reg < 16; ++reg){
        int row = (reg & 3) + 8*(reg >> 2) + 4*(l >> 5);
        int it2 = row >> 4, q2 = row & 15;
        x3_s[it2*4224 + q2*264 + col] = (_Float16)fmaxf(acc[reg] + bias, 0.f);
      }
    }
  }
  __syncthreads();
  { // gi stacked M=32; wave -> n-tiles {6w .. 6w+5}, N=768
    const int r0 = ((2*p) >> 6)*16, t0 = (2*p) & 63;
    const int ito = r32 >> 4, qr = r32 & 15;
#pragma unroll
    for (int s = 0; s < 6; ++s){
      int nt = 6*w + s;
      f32x16 acc = 0.f;
      for (int kk = 0; kk < 16; ++kk){
        f16x8 A = *(const f16x8*)(x3_s + ito*4224 + qr*264 + kk*16 + kh);
        f16x8 B = *(const f16x8*)(GIHT + (size_t)(nt*32 + r32)*256 + kk*16 + kh);
        acc = mfma32(A, B, acc);
      }
      int col = nt*32 + r32;
      float bias = gib[col];
#pragma unroll
      for (int reg = 0; reg < 16; ++reg){
        int row = (reg & 3) + 8*(reg >> 2) + 4*(l >> 5);
        int it2 = row >> 4, q2 = row & 15;
        gi[((size_t)((r0 + q2)*64 + t0 + it2))*768 + col] = acc[reg] + bias;
      }
    }
  }
}

// ------------------------------------------------------------------ K3: GRU
// r21: 512 threads (r18-verified structure) + gi register double-buffer:
// step t+1's gi loads issue before step t's MFMA so HBM latency hides under
// compute instead of serializing the 64-step chain.
__global__ __launch_bounds__(512) void k3_gru(
    const _Float16* __restrict__ WHH, const float* __restrict__ bhh,
    const float* __restrict__ gi, const float* __restrict__ h0,
    float* __restrict__ hs)
{
  const int rb = blockIdx.x;
  const int row0 = rb * 16;
  const int tid = threadIdx.x;
  const int w = tid >> 6, lg = (tid >> 4) & 3, li = tid & 15;

  extern __shared__ char smem3[];
  _Float16* hf16 = (_Float16*)smem3;
  float* hf32 = (float*)(smem3 + 8448);
  float* gh   = (float*)(smem3 + 8448 + 16640);
  float* bhs  = (float*)(smem3 + 8448 + 16640 + 49664);

  for (int idx = tid; idx < 768; idx += 512) bhs[idx] = bhh[idx];
  for (int idx = tid; idx < 4096; idx += 512){
    int r = idx >> 8, d = idx & 255;
    float v = h0[(size_t)(row0 + r)*256 + d];
    hf32[r*260 + d] = v;
    hf16[r*264 + d] = (_Float16)v;
  }
  __syncthreads();

  const int er = tid >> 5;
  const int dd = (tid & 31) * 8;
  const float* gbase = gi + ((size_t)(row0 + er)*64)*768 + dd;

  f32x4 gr[2], gz[2], gn[2];
#pragma unroll
  for (int v = 0; v < 2; ++v){
    gr[v] = *(const f32x4*)(gbase + v*4);
    gz[v] = *(const f32x4*)(gbase + 256 + v*4);
    gn[v] = *(const f32x4*)(gbase + 512 + v*4);
  }

  for (int t = 0; t < 64; ++t){
    // prefetch next step's gi while this step computes
    f32x4 nr[2], nz[2], nn_[2];
    if (t < 63){
      const float* gp = gbase + (size_t)(t + 1)*768;
#pragma unroll
      for (int v = 0; v < 2; ++v){
        nr[v]  = *(const f32x4*)(gp + v*4);
        nz[v]  = *(const f32x4*)(gp + 256 + v*4);
        nn_[v] = *(const f32x4*)(gp + 512 + v*4);
      }
    }
    f16x8 a[8];
#pragma unroll
    for (int kk = 0; kk < 8; ++kk)
      a[kk] = *(const f16x8*)(hf16 + li*264 + kk*32 + lg*8);
    f32x4 acc[6];
#pragma unroll
    for (int c = 0; c < 6; ++c) acc[c] = 0.f;
#pragma unroll
    for (int c = 0; c < 6; ++c){
      const _Float16* bp = WHH + (size_t)(w*96 + c*16 + li)*256 + lg*8;
#pragma unroll
      for (int kk = 0; kk < 8; ++kk)
        acc[c] = mfma16(a[kk], *(const f16x8*)(bp + kk*32), acc[c]);
    }
#pragma unroll
    for (int c = 0; c < 6; ++c){
      int col = w*96 + c*16 + li;
#pragma unroll
      for (int j = 0; j < 4; ++j)
        gh[(4*lg + j)*776 + col] = acc[c][j];
    }
    __syncthreads();
    {
      float* hp32 = hf32 + er*260 + dd;
      float* hsp  = hs + ((size_t)(rb*64 + t)*16 + er)*256 + dd;
      f16x8 hv8;
#pragma unroll
      for (int v = 0; v < 2; ++v){
        f32x4 xr = *(const f32x4*)(gh + er*776 +       dd + v*4);
        f32x4 xz = *(const f32x4*)(gh + er*776 + 256 + dd + v*4);
        f32x4 xn = *(const f32x4*)(gh + er*776 + 512 + dd + v*4);
        f32x4 hold = *(const f32x4*)(hp32 + v*4);
        f32x4 hout;
#pragma unroll
        for (int e = 0; e < 4; ++e){
          int d = dd + v*4 + e;
          float rr_ = 1.f/(1.f + __expf(-(gr[v][e] + xr[e] + bhs[d])));
          float zz  = 1.f/(1.f + __expf(-(gz[v][e] + xz[e] + bhs[256 + d])));
          float pre = gn[v][e] + rr_*(xn[e] + bhs[512 + d]);
          float nn  = 1.f - 2.f/(1.f + __expf(2.f*pre));
          float hv = (1.f - zz)*nn + zz*hold[e];
          hout[e] = hv;
          hv8[v*4 + e] = (_Float16)hv;
        }
        *(f32x4*)(hp32 + v*4) = hout;
        *(f32x4*)(hsp + v*4)  = hout;
      }
      *(f16x8*)(hf16 + er*264 + dd) = hv8;
    }
    __syncthreads();
    if (t < 63){
#pragma unroll
      for (int v = 0; v < 2; ++v){ gr[v] = nr[v]; gz[v] = nz[v]; gn[v] = nn_[v]; }
    }
  }
}

// ------------------------------------------------------------------ K4: q out
__global__ __launch_bounds__(256) void k4_q(
    const _Float16* __restrict__ FC3T, const float* __restrict__ fc3b,
    const float* __restrict__ em, const float* __restrict__ hs, float* __restrict__ qo)
{
  const int tid = threadIdx.x;
  const int w = tid >> 6, lg = (tid >> 4) & 3, li = tid & 15;
  const int rb = blockIdx.x*64 + 16*w;
  f32x4 acc[2];
#pragma unroll
  for (int c = 0; c < 2; ++c) acc[c] = 0.f;
  for (int kk = 0; kk < 8; ++kk){
    const float* ap = hs + (size_t)(rb + li)*256 + kk*32 + lg*8;
    f32x4 v0 = *(const f32x4*)ap, v1 = *(const f32x4*)(ap + 4);
    f16x8 A;
#pragma unroll
    for (int e = 0; e < 4; ++e){ A[e] = (_Float16)v0[e]; A[e+4] = (_Float16)v1[e]; }
#pragma unroll
    for (int c = 0; c < 2; ++c){
      f16x8 B = *(const f16x8*)(FC3T + (size_t)(16*c + li)*256 + kk*32 + lg*8);
      acc[c] = mfma16(A, B, acc[c]);
    }
  }
#pragma unroll
  for (int c = 0; c < 2; ++c){
    int col = 16*c + li;
    float bias = fc3b[col];
#pragma unroll
    for (int j = 0; j < 4; ++j){
      int row = rb + 4*lg + j;
      float am = em[(size_t)(row >> 4)*64 + (row & 15)];
      qo[(size_t)row*32 + col] = (acc[c][j] + bias)*(1.f - am);
    }
  }
}

// --------------------------------------------------------------------- launch
extern "C" void kernel_launch(void* const* d_in, const int* in_sizes, int n_in,
                              void* d_out, int out_size, void* d_ws, size_t ws_size,
                              hipStream_t stream)
{
  constexpr size_t OFF_FC1T   = 0;
  constexpr size_t OFF_MSG1T  = 49152;
  constexpr size_t OFF_AINT   = 98304;
  constexpr size_t OFF_LINT   = 491520;
  constexpr size_t OFF_AOUTT  = 884736;
  constexpr size_t OFF_LOUTT  = 1015808;
  constexpr size_t OFF_GMINT  = 1146880;
  constexpr size_t OFF_GMOUTT = 1540096;
  constexpr size_t OFF_FC2T   = 1671168;
  constexpr size_t OFF_GIHT   = 1933312;
  constexpr size_t OFF_GHHT   = 2326528;
  constexpr size_t OFF_FC3T   = 2719744;
  constexpr size_t OFF_G1T    = 2736128;
  constexpr size_t OFF_GINT   = 2834432;
  constexpr size_t OFF_WVEFF  = 3620864;
  constexpr size_t OFF_BEFF   = 3637248;
  constexpr size_t OFF_GATE   = 3637504;
  constexpr size_t OFF_X2     = 3768576;
  constexpr size_t OFF_X2M    = 37323008;
  constexpr size_t OFF_GI     = 70877440;
  constexpr size_t NEED       = 171540736;
  if (ws_size < NEED) return;

  char* ws = (char*)d_ws;
  const float* ent = (const float*)d_in[0];
  const float* om  = (const float*)d_in[1];
  const float* em  = (const float*)d_in[2];

  WJobs jb{};
  int nj = 0;
  auto addj = [&](int src_idx, size_t off, int K, int N, int m){
    jb.src[nj] = (const float*)d_in[src_idx]; jb.off[nj] = (unsigned)off;
    jb.K[nj] = K; jb.N[nj] = N; jb.mode[nj] = m; ++nj;
  };
  addj(4,  OFF_FC1T,   96, 256, 0);
  addj(17, OFF_MSG1T,  96, 256, 0);
  addj(6,  OFF_AINT,  256, 768, 0);
  addj(19, OFF_LINT,  256, 768, 0);
  addj(7,  OFF_AOUTT, 256, 256, 0);
  addj(20, OFF_LOUTT, 256, 256, 0);
  addj(22, OFF_GMINT, 256, 768, 0);
  addj(23, OFF_GMOUTT,256, 256, 0);
  addj(9,  OFF_FC2T,  512, 256, 0);
  addj(11, OFF_GIHT,  256, 768, 0);
  addj(12, OFF_GHHT,  256, 768, 0);
  addj(15, OFF_FC3T,  256,  32, 0);
  addj(28, OFF_G1T,    96, 256, 1);
  addj(25, OFF_GINT,  256, 768, 1);
  k0_conv<<<dim3(96, nj), 256, 0, stream>>>(jb, ws);

  k0w_gate<<<1, 256, 0, stream>>>(
      (const float*)d_in[26], (const float*)d_in[30],
      (const float*)d_in[27], (const float*)d_in[25],
      (_Float16*)(ws + OFF_WVEFF), (float*)(ws + OFF_BEFF));

  constexpr int SMB = 156672, SMK2 = 131200, SM3 = 77824;
  (void)hipFuncSetAttribute(reinterpret_cast<const void*>(&k1_all),
                            hipFuncAttributeMaxDynamicSharedMemorySize, SMB);
  (void)hipFuncSetAttribute(reinterpret_cast<const void*>(&k2_global),
                            hipFuncAttributeMaxDynamicSharedMemorySize, SMK2);
  (void)hipFuncSetAttribute(reinterpret_cast<const void*>(&k3_gru),
                            hipFuncAttributeMaxDynamicSharedMemorySize, SM3);

  float* qout = (float*)d_out;
  float* hsout = qout + 1048576;
  float* gout = qout + 9437184;

  k1_all<<<4096, 512, SMB, stream>>>(ent, om, em,
      (const _Float16*)(ws + OFF_FC1T),  (const float*)d_in[5],
      (const _Float16*)(ws + OFF_AINT),
      (const _Float16*)(ws + OFF_AOUTT), (const float*)d_in[8],
      (float*)(ws + OFF_X2),
      (const _Float16*)(ws + OFF_MSG1T), (const float*)d_in[18],
      (const _Float16*)(ws + OFF_LINT),
      (const _Float16*)(ws + OFF_LOUTT), (const float*)d_in[21],
      (float*)(ws + OFF_X2M),
      (const _Float16*)(ws + OFF_G1T),   (const float*)d_in[29],
      (const _Float16*)(ws + OFF_GINT),
      (const _Float16*)(ws + OFF_WVEFF),
      (const float*)(ws + OFF_BEFF), (const float*)d_in[31],
      gout, (float*)(ws + OFF_GATE));

  k2_global<<<1024, 256, SMK2, stream>>>(em,
      (const float*)(ws + OFF_X2), (const float*)(ws + OFF_X2M),
      (const float*)(ws + OFF_GATE),
      (const _Float16*)(ws + OFF_GMINT), (const _Float16*)(ws + OFF_GMOUTT), (const float*)d_in[24],
      (const _Float16*)(ws + OFF_FC2T), (const float*)d_in[10],
      (const _Float16*)(ws + OFF_GIHT), (const float*)d_in[13],
      (float*)(ws + OFF_GI));

  k3_gru<<<32, 512, SM3, stream>>>(
      (const _Float16*)(ws + OFF_GHHT), (const float*)d_in[14],
      (const float*)(ws + OFF_GI), (const float*)d_in[3], hsout);

  k4_q<<<512, 256, 0, stream>>>(
      (const _Float16*)(ws + OFF_FC3T), (const float*)d_in[16],
      em, hsout, qout);
}

// Round 22
// 1073.751 us; speedup vs baseline: 1.2081x; 1.1732x over previous
//
#include <hip/hip_runtime.h>

// EntityAttentionRNNMsgAgent — fused MI355X implementation.
// r22 = r19 + k2 at 512 threads (8 waves, halved per-wave tile counts:
// QKV/gi 3 tiles/wave, gmsg/fc2 1, PV via (it=w&1, dt=w>>1); same LDS and
// barrier structure — occupancy 4->8 waves/CU on the 131KB-LDS kernel).
// k3 reverted to the r18/r19-verified 512-thread version (r21's prefetch
// spilled and regressed). k1_all / k0 / k0w / k4 byte-identical to r19
// (1143.6us verified).

#define DEV __device__ __forceinline__

typedef _Float16 f16x8 __attribute__((ext_vector_type(8)));
typedef _Float16 f16x4 __attribute__((ext_vector_type(4)));
typedef float    f32x4 __attribute__((ext_vector_type(4)));
typedef float    f32x16 __attribute__((ext_vector_type(16)));

DEV f32x4 mfma16(f16x8 a, f16x8 b, f32x4 c){
  return __builtin_amdgcn_mfma_f32_16x16x32_f16(a, b, c, 0, 0, 0);
}
DEV f32x16 mfma32(f16x8 a, f16x8 b, f32x16 c){
  return __builtin_amdgcn_mfma_f32_32x32x16_f16(a, b, c, 0, 0, 0);
}

// A/B fragment pair for optional split-precision (MODE=1: value = hi + lo)
template<int MODE> struct AB {
  f16x8 hi, lo;
  DEV void mf(const AB& b, f32x4& c) const {
    if constexpr (MODE){
      c = mfma16(lo, b.hi, c);
      c = mfma16(hi, b.lo, c);
    }
    c = mfma16(hi, b.hi, c);
  }
};

template<int MODE> DEV AB<MODE> ldW(const _Float16* p, int losz){
  AB<MODE> r; r.hi = *(const f16x8*)p;
  if constexpr (MODE) r.lo = *(const f16x8*)(p + losz);
  return r;
}
template<int MODE> DEV AB<MODE> ldL(const _Float16* ph, const _Float16* pl){
  AB<MODE> r; r.hi = *(const f16x8*)ph;
  if constexpr (MODE) r.lo = *(const f16x8*)pl;
  return r;
}
template<int MODE> DEV AB<MODE> ldF(const float* p){
  AB<MODE> r;
  f32x4 v0 = *(const f32x4*)p, v1 = *(const f32x4*)(p + 4);
#pragma unroll
  for (int i = 0; i < 4; ++i){
    float a = v0[i], b = v1[i];
    _Float16 ah = (_Float16)a, bh = (_Float16)b;
    r.hi[i] = ah; r.hi[i+4] = bh;
    if constexpr (MODE){
      r.lo[i]   = (_Float16)(a - (float)ah);
      r.lo[i+4] = (_Float16)(b - (float)bh);
    }
  }
  return r;
}
template<int MODE> DEV void stL(_Float16* ph, _Float16* pl, int idx, float v){
  _Float16 h = (_Float16)v;
  ph[idx] = h;
  if constexpr (MODE) pl[idx] = (_Float16)(v - (float)h);
}

// ---------------------------------------------------------------- K0: weights
struct WJobs {
  const float* src[15];
  unsigned off[15];
  int K[15], N[15], mode[15];
};

__global__ __launch_bounds__(256) void k0_conv(WJobs jb, char* ws){
  const int job = blockIdx.y;
  const int K = jb.K[job], N = jb.N[job];
  const int total = K * N;
  _Float16* dh = (_Float16*)(ws + jb.off[job]);
  const float* src = jb.src[job];
  const int m = jb.mode[job];
  for (int idx = blockIdx.x*256 + threadIdx.x; idx < total; idx += gridDim.x*256){
    int n = idx / K, k = idx - n*K;
    float v = src[(size_t)k*N + n];
    _Float16 h = (_Float16)v;
    dh[idx] = h;
    if (m) dh[total + idx] = (_Float16)(v - (float)h);
  }
}

// ------------------------------------------------- K0w: gate-tail precompute
__global__ __launch_bounds__(256) void k0w_gate(
    const float* __restrict__ Wout, const float* __restrict__ Wg2,
    const float* __restrict__ bo,   const float* __restrict__ Win,
    _Float16* __restrict__ wveff, float* __restrict__ beff)
{
  __shared__ float weff_s[256*2];
  const int tid = threadIdx.x;
  {
    float a0 = 0.f, a1 = 0.f;
    const float* wr = Wout + (size_t)tid*256;
    for (int f = 0; f < 256; ++f){ float x = wr[f]; a0 += x*Wg2[2*f]; a1 += x*Wg2[2*f+1]; }
    weff_s[tid*2] = a0; weff_s[tid*2+1] = a1;
  }
  if (tid < 2){
    float s = 0.f;
    for (int f = 0; f < 256; ++f) s += bo[f]*Wg2[2*f + tid];
    beff[tid] = s;
  }
  __syncthreads();
  {
    const int j = tid;
    for (int n = 0; n < 16; ++n){
      float v = 0.f;
      if (n < 8){
        int h = n >> 1, c = n & 1;
        const float* wr = Win + (size_t)j*768 + 512 + h*64;
        const float* we = weff_s + (h*64)*2 + c;
        for (int d = 0; d < 64; ++d) v += wr[d]*we[2*d];
      }
      _Float16 hi = (_Float16)v;
      wveff[n*256 + j] = hi;
      wveff[16*256 + n*256 + j] = (_Float16)(v - (float)hi);
    }
  }
}

// -------------------------------------------- K1 fused: branch2 + gate roles
__global__ __launch_bounds__(512) void k1_all(
    const float* __restrict__ ent, const float* __restrict__ om, const float* __restrict__ em,
    const _Float16* __restrict__ W1a, const float* __restrict__ b1a,
    const _Float16* __restrict__ WINa,
    const _Float16* __restrict__ WOUTa, const float* __restrict__ boa,
    float* __restrict__ x2outa,
    const _Float16* __restrict__ W1b, const float* __restrict__ b1b,
    const _Float16* __restrict__ WINb,
    const _Float16* __restrict__ WOUTb, const float* __restrict__ bob,
    float* __restrict__ x2outb,
    const _Float16* __restrict__ W1g, const float* __restrict__ b1g,
    const _Float16* __restrict__ WINg,
    const _Float16* __restrict__ WVEFF,
    const float* __restrict__ beff, const float* __restrict__ gb2,
    float* __restrict__ og, float* __restrict__ gate)
{
  const int tid = threadIdx.x;
  const int w = tid >> 6, lg = (tid >> 4) & 3, li = tid & 15;
  extern __shared__ char smem[];

  if (blockIdx.x < 2048){
    // ============================ branch2 role ============================
    const int br = blockIdx.x >> 10;
    const int p  = blockIdx.x & 1023;
    const int bb2[2] = { 2*p, 2*p + 1 };
    const _Float16* W1   = br ? W1b   : W1a;
    const float*    b1   = br ? b1b   : b1a;
    const _Float16* WIN  = br ? WINb  : WINa;
    const _Float16* WOUT = br ? WOUTb : WOUTa;
    const float*    bo   = br ? bob   : boa;
    float*          x2out= br ? x2outb: x2outa;

    const int wi = w & 3, ih = w >> 2;
    const int l = tid & 63;
    const int r32 = l & 31, kh = (l >> 5)*8;

    _Float16* x1   = (_Float16*)smem;
    _Float16* Ks   = (_Float16*)(smem + 67584);
    _Float16* Vs   = (_Float16*)(smem + 86016);
    _Float16* Qful = (_Float16*)(smem + 104448);
    float*    lgs  = (float*)(smem + 121344);
    _Float16* Ps   = (_Float16*)(smem + 130560);
    _Float16* outp = (_Float16*)(smem + 135168);

    { // phase 1: x1 = relu(ent @ W1 + b1) via 32x32x16
      const int b = bb2[ih];
      _Float16* x1p = x1 + ih*16896;
      const int mt = wi & 1, ntb = (wi >> 1)*4;
      f32x16 acc0 = 0.f, acc1 = 0.f, acc2 = 0.f, acc3 = 0.f;
#pragma unroll
      for (int kk = 0; kk < 6; ++kk){
        AB<0> a = ldF<0>(ent + ((size_t)b*64 + mt*32 + r32)*96 + kk*16 + kh);
        f16x8 B0 = *(const f16x8*)(W1 + (size_t)((ntb + 0)*32 + r32)*96 + kk*16 + kh);
        f16x8 B1 = *(const f16x8*)(W1 + (size_t)((ntb + 1)*32 + r32)*96 + kk*16 + kh);
        f16x8 B2 = *(const f16x8*)(W1 + (size_t)((ntb + 2)*32 + r32)*96 + kk*16 + kh);
        f16x8 B3 = *(const f16x8*)(W1 + (size_t)((ntb + 3)*32 + r32)*96 + kk*16 + kh);
        acc0 = mfma32(a.hi, B0, acc0);
        acc1 = mfma32(a.hi, B1, acc1);
        acc2 = mfma32(a.hi, B2, acc2);
        acc3 = mfma32(a.hi, B3, acc3);
      }
#pragma unroll
      for (int s = 0; s < 4; ++s){
        const f32x16& ac = (s == 0) ? acc0 : (s == 1) ? acc1 : (s == 2) ? acc2 : acc3;
        int col = (ntb + s)*32 + r32;
        float bias = b1[col];
#pragma unroll
        for (int reg = 0; reg < 16; ++reg){
          int row = (reg & 3) + 8*(reg >> 2) + 4*(l >> 5);
          x1p[(mt*32 + row)*264 + col] = (_Float16)fmaxf(ac[reg] + bias, 0.f);
        }
      }
    }
    __syncthreads();

    { // Qfull = x1[rows 0..15, both items stacked M=32] @ Wq; wave -> n-tile w
      f32x16 acc = 0.f;
      const int itq = r32 >> 4, qr = r32 & 15;
      for (int kk = 0; kk < 16; ++kk){
        f16x8 A = *(const f16x8*)(x1 + itq*16896 + qr*264 + kk*16 + kh);
        f16x8 B = *(const f16x8*)(WIN + (size_t)(w*32 + r32)*256 + kk*16 + kh);
        acc = mfma32(A, B, acc);
      }
#pragma unroll
      for (int reg = 0; reg < 16; ++reg){
        int row = (reg & 3) + 8*(reg >> 2) + 4*(l >> 5);
        Qful[(row >> 4)*4224 + (row & 15)*264 + w*32 + r32] = (_Float16)acc[reg];
      }
    }
    __syncthreads();

    for (int h = 0; h < 4; ++h){
      if (w < 4){
        const int kt = w >> 1, dt = w & 1;
        f32x16 acc0 = 0.f, acc1 = 0.f;
        for (int kk = 0; kk < 16; ++kk){
          int ao = (kt*32 + r32)*264 + kk*16 + kh;
          f16x8 A0 = *(const f16x8*)(x1 + ao);
          f16x8 A1 = *(const f16x8*)(x1 + 16896 + ao);
          f16x8 B = *(const f16x8*)(WIN + (size_t)(256 + 64*h + dt*32 + r32)*256 + kk*16 + kh);
          acc0 = mfma32(A0, B, acc0);
          acc1 = mfma32(A1, B, acc1);
        }
#pragma unroll
        for (int reg = 0; reg < 16; ++reg){
          int row = (reg & 3) + 8*(reg >> 2) + 4*(l >> 5);
          Ks[(kt*32 + row)*72 + dt*32 + r32]        = (_Float16)acc0[reg];
          Ks[4608 + (kt*32 + row)*72 + dt*32 + r32] = (_Float16)acc1[reg];
        }
      } else {
        const int wv = w - 4;
        const int kt = wv >> 1, dt = wv & 1;
        f32x16 acc0 = 0.f, acc1 = 0.f;
        for (int kk = 0; kk < 16; ++kk){
          int ao = (kt*32 + r32)*264 + kk*16 + kh;
          f16x8 A0 = *(const f16x8*)(x1 + ao);
          f16x8 A1 = *(const f16x8*)(x1 + 16896 + ao);
          f16x8 B = *(const f16x8*)(WIN + (size_t)(512 + 64*h + dt*32 + r32)*256 + kk*16 + kh);
          acc0 = mfma32(A0, B, acc0);
          acc1 = mfma32(A1, B, acc1);
        }
#pragma unroll
        for (int rr = 0; rr < 4; ++rr){
          f16x4 p0, p1;
#pragma unroll
          for (int q4 = 0; q4 < 4; ++q4){
            p0[q4] = (_Float16)acc0[rr*4 + q4];
            p1[q4] = (_Float16)acc1[rr*4 + q4];
          }
          int key = kt*32 + rr*8 + 4*(l >> 5);
          *(f16x4*)(Vs + (dt*32 + r32)*72 + key)        = p0;
          *(f16x4*)(Vs + 4608 + (dt*32 + r32)*72 + key) = p1;
        }
      }
      __syncthreads();
      { // logits: A from Qful
        const int b = bb2[ih];
        f32x4 acc = 0.f;
#pragma unroll
        for (int kk = 0; kk < 2; ++kk){
          f16x8 A = *(const f16x8*)(Qful + ih*4224 + li*264 + 64*h + kk*32 + lg*8);
          f16x8 B = *(const f16x8*)(Ks + ih*4608 + (16*wi + li)*72 + kk*32 + lg*8);
          acc = mfma16(A, B, acc);
        }
#pragma unroll
        for (int j = 0; j < 4; ++j){
          int q = 4*lg + j, key = 16*wi + li;
          float v = acc[j] * 0.125f;
          float m = om[((size_t)b*64 + q)*64 + key];
          if (m > 0.f) v = -1e9f;
          lgs[ih*1152 + q*72 + key] = v;
        }
      }
      __syncthreads();
      { // softmax
        const int it = tid >> 8, q = (tid >> 4) & 15, i16 = tid & 15;
        const int b = bb2[it];
        float pv[4], mx = -3e38f;
#pragma unroll
        for (int u = 0; u < 4; ++u){ pv[u] = lgs[it*1152 + q*72 + i16 + 16*u]; mx = fmaxf(mx, pv[u]); }
#pragma unroll
        for (int d = 1; d < 16; d <<= 1) mx = fmaxf(mx, __shfl_xor(mx, d, 16));
        float s = 0.f;
#pragma unroll
        for (int u = 0; u < 4; ++u){ pv[u] = expf(pv[u] - mx); s += pv[u]; }
#pragma unroll
        for (int d = 1; d < 16; d <<= 1) s += __shfl_xor(s, d, 16);
#pragma unroll
        for (int u = 0; u < 4; ++u){
          int key = i16 + 16*u;
          float m = om[((size_t)b*64 + q)*64 + key];
          Ps[it*1152 + q*72 + key] = (_Float16)((pv[u]/s)*(1.f - m));
        }
      }
      __syncthreads();
      { // out_h = P @ V_h; outp stored f16
        f32x4 acc = 0.f;
#pragma unroll
        for (int kk = 0; kk < 2; ++kk){
          f16x8 A = *(const f16x8*)(Ps + ih*1152 + li*72 + kk*32 + lg*8);
          f16x8 B = *(const f16x8*)(Vs + ih*4608 + (16*wi + li)*72 + kk*32 + lg*8);
          acc = mfma16(A, B, acc);
        }
#pragma unroll
        for (int j = 0; j < 4; ++j)
          outp[ih*4224 + (4*lg + j)*264 + 64*h + 16*wi + li] = (_Float16)acc[j];
      }
      __syncthreads();
    }

    { // out-proj via 32x32, stacked M=32; wave -> n-tile w
      f32x16 acc = 0.f;
      const int ito = r32 >> 4, qr = r32 & 15;
      for (int kk = 0; kk < 16; ++kk){
        f16x8 A = *(const f16x8*)(outp + ito*4224 + qr*264 + kk*16 + kh);
        f16x8 B = *(const f16x8*)(WOUT + (size_t)(w*32 + r32)*256 + kk*16 + kh);
        acc = mfma32(A, B, acc);
      }
      int col = w*32 + r32;
      float bias = bo[col];
#pragma unroll
      for (int reg = 0; reg < 16; ++reg){
        int row = (reg & 3) + 8*(reg >> 2) + 4*(l >> 5);
        int it2 = row >> 4, q2 = row & 15;
        const int b = bb2[it2];
        float v = (acc[reg] + bias) * (1.f - em[(size_t)b*64 + q2]);
        x2out[((size_t)b*16 + q2)*256 + col] = v;
      }
    }
    return;
  }

  // ============================== gate role ==============================
  {
    constexpr int W1SZ = 96*256, WINSZ = 256*768, WVSZ = 16*256;
    const int b = blockIdx.x - 2048;
    const int l = tid & 63;
    const int r32 = l & 31, kh = (l >> 5)*8;

    char* sp = smem;
    _Float16* x1h = (_Float16*)sp; sp += 64*264*2;
    _Float16* x1l = (_Float16*)sp; sp += 64*264*2;
    _Float16* Kh  = (_Float16*)sp; sp += 64*72*2;
    _Float16* Kl  = (_Float16*)sp; sp += 64*72*2;
    _Float16* Qh  = (_Float16*)sp; sp += 16*264*2;
    _Float16* Ql  = (_Float16*)sp; sp += 16*264*2;
    float*    lgs = (float*)sp;    sp += 16*72*4;
    float*    Ps  = (float*)sp;    sp += 16*66*4;
    float*    v2s = (float*)sp;    sp += 64*18*4;
    float*  ogacc = (float*)sp;    sp += 32*4;
    float*  Kpart = (float*)sp;    sp += 8192*4;

    { // phase 1: x1 = relu(ent @ W1g + b1g), 32x32 split-2
      const int mt = w & 1, ntb = (w >> 1)*2;
      f32x16 acc0 = 0.f, acc1 = 0.f;
#pragma unroll
      for (int kk = 0; kk < 6; ++kk){
        AB<1> a = ldF<1>(ent + ((size_t)b*64 + mt*32 + r32)*96 + kk*16 + kh);
#pragma unroll
        for (int s = 0; s < 2; ++s){
          const _Float16* bp = W1g + (size_t)((ntb + s)*32 + r32)*96 + kk*16 + kh;
          f16x8 Bh = *(const f16x8*)bp;
          f16x8 Bl = *(const f16x8*)(bp + W1SZ);
          f32x16& ac = s ? acc1 : acc0;
          ac = mfma32(a.lo, Bh, ac);
          ac = mfma32(a.hi, Bl, ac);
          ac = mfma32(a.hi, Bh, ac);
        }
      }
#pragma unroll
      for (int s = 0; s < 2; ++s){
        const f32x16& ac = s ? acc1 : acc0;
        int col = (ntb + s)*32 + r32;
        float bias = b1g[col];
#pragma unroll
        for (int reg = 0; reg < 16; ++reg){
          int row = (reg & 3) + 8*(reg >> 2) + 4*(l >> 5);
          stL<1>(x1h, x1l, (mt*32 + row)*264 + col, fmaxf(ac[reg] + bias, 0.f));
        }
      }
    }
    if (tid < 32) ogacc[tid] = 0.f;
    __syncthreads();

    { // phase 2: Qfull (16x16 split-2), v2
#pragma unroll
      for (int s = 0; s < 2; ++s){
        int nt = w + s*8;
        f32x4 acc = 0.f;
        for (int kk = 0; kk < 8; ++kk){
          int ao = li*264 + kk*32 + lg*8;
          AB<1> a = ldL<1>(x1h + ao, x1l + ao);
          AB<1> bb = ldW<1>(WINg + (size_t)(nt*16 + li)*256 + kk*32 + lg*8, WINSZ);
          a.mf(bb, acc);
        }
#pragma unroll
        for (int j = 0; j < 4; ++j)
          stL<1>(Qh, Ql, (4*lg + j)*264 + nt*16 + li, acc[j]);
      }
      if (w < 4){
        f32x4 acc = 0.f;
        for (int kk = 0; kk < 8; ++kk){
          int ao = (w*16 + li)*264 + kk*32 + lg*8;
          AB<1> a = ldL<1>(x1h + ao, x1l + ao);
          AB<1> bb = ldW<1>(WVEFF + (size_t)li*256 + kk*32 + lg*8, WVSZ);
          a.mf(bb, acc);
        }
#pragma unroll
        for (int j = 0; j < 4; ++j)
          v2s[(w*16 + 4*lg + j)*18 + li] = acc[j];
      }
    }
    __syncthreads();

    for (int h = 0; h < 4; ++h){
      { // K_h partials: 32x32 split-2, tiles x k-halves across 8 waves
        const int t = w & 3, kt = t >> 1, dt = t & 1, khalf = w >> 2;
        f32x16 acc = 0.f;
#pragma unroll
        for (int k8 = 0; k8 < 8; ++k8){
          int ko = (khalf*8 + k8)*16 + kh;
          int ao = (kt*32 + r32)*264 + ko;
          f16x8 ah = *(const f16x8*)(x1h + ao);
          f16x8 al = *(const f16x8*)(x1l + ao);
          const _Float16* bp = WINg + (size_t)(256 + h*64 + dt*32 + r32)*256 + ko;
          f16x8 Bh = *(const f16x8*)bp;
          f16x8 Bl = *(const f16x8*)(bp + WINSZ);
          acc = mfma32(al, Bh, acc);
          acc = mfma32(ah, Bl, acc);
          acc = mfma32(ah, Bh, acc);
        }
#pragma unroll
        for (int reg = 0; reg < 16; ++reg){
          int row = (reg & 3) + 8*(reg >> 2) + 4*(l >> 5);
          Kpart[((khalf*4 + t)*32 + row)*32 + r32] = acc[reg];
        }
      }
      __syncthreads();
      { // reduce k-halves -> Kh/Kl
        for (int e = tid; e < 4096; e += 512){
          float s2 = Kpart[e] + Kpart[4096 + e];
          int t2 = e >> 10, idx = e & 1023, row = idx >> 5, col = idx & 31;
          stL<1>(Kh, Kl, ((t2 >> 1)*32 + row)*72 + (t2 & 1)*32 + col, s2);
        }
      }
      __syncthreads();
      if (w < 4){ // logits
        f32x4 acc = 0.f;
#pragma unroll
        for (int kk = 0; kk < 2; ++kk){
          int ao = li*264 + h*64 + kk*32 + lg*8;
          AB<1> a = ldL<1>(Qh + ao, Ql + ao);
          int bo_ = (16*w + li)*72 + kk*32 + lg*8;
          AB<1> bb = ldL<1>(Kh + bo_, Kl + bo_);
          a.mf(bb, acc);
        }
#pragma unroll
        for (int j = 0; j < 4; ++j){
          int q = 4*lg + j, key = 16*w + li;
          float v = acc[j] * 0.125f;
          float m = om[((size_t)b*64 + q)*64 + key];
          if (m > 0.f) v = -1e9f;
          lgs[q*72 + key] = v;
        }
      }
      __syncthreads();
      if (tid < 256){ // softmax
        int q = tid >> 4, i16 = tid & 15;
        float pv[4], mx = -3e38f;
#pragma unroll
        for (int u = 0; u < 4; ++u){ pv[u] = lgs[q*72 + i16 + 16*u]; mx = fmaxf(mx, pv[u]); }
#pragma unroll
        for (int d = 1; d < 16; d <<= 1) mx = fmaxf(mx, __shfl_xor(mx, d, 16));
        float s = 0.f;
#pragma unroll
        for (int u = 0; u < 4; ++u){ pv[u] = expf(pv[u] - mx); s += pv[u]; }
#pragma unroll
        for (int d = 1; d < 16; d <<= 1) s += __shfl_xor(s, d, 16);
#pragma unroll
        for (int u = 0; u < 4; ++u){
          int key = i16 + 16*u;
          float m = om[((size_t)b*64 + q)*64 + key];
          Ps[q*66 + key] = (pv[u]/s)*(1.f - m);
        }
      }
      __syncthreads();
      if (tid < 256){ // og += P_h . v2_h
        int q = tid >> 4, l16 = tid & 15;
        float a0 = 0.f, a1 = 0.f;
#pragma unroll
        for (int u = 0; u < 4; ++u){
          int k = l16 + 16*u;
          float p2 = Ps[q*66 + k];
          a0 += p2 * v2s[k*18 + h*2];
          a1 += p2 * v2s[k*18 + h*2 + 1];
        }
#pragma unroll
        for (int d = 1; d < 16; d <<= 1){ a0 += __shfl_xor(a0, d, 16); a1 += __shfl_xor(a1, d, 16); }
        if (l16 == 0){ ogacc[q*2] += a0; ogacc[q*2 + 1] += a1; }
      }
      __syncthreads();
    }
    if (tid < 16){
      int q = tid;
      float am = em[(size_t)b*64 + q];
      float g0 = (1.f - am)*(ogacc[2*q]     + beff[0]) + gb2[0];
      float g1 = (1.f - am)*(ogacc[2*q + 1] + beff[1]) + gb2[1];
      og[((size_t)b*16 + q)*2]     = g0;
      og[((size_t)b*16 + q)*2 + 1] = g1;
      gate[(size_t)b*16 + q] = (g1 > g0) ? 1.f : 0.f;
    }
  }
}

// ------------------- K2: gate, global attention, fc2, gi — 2 items/block
// r22: 512 threads (8 waves). Per-wave tile counts halved everywhere; LDS
// and barrier structure identical to r19.
__global__ __launch_bounds__(512) void k2_global(
    const float* __restrict__ em,
    const float* __restrict__ x2, const float* __restrict__ x2m,
    const float* __restrict__ gate,
    const _Float16* __restrict__ GMIN, const _Float16* __restrict__ GMOUT, const float* __restrict__ gob,
    const _Float16* __restrict__ FC2T, const float* __restrict__ fc2b,
    const _Float16* __restrict__ GIHT, const float* __restrict__ gib,
    float* __restrict__ gi)
{
  const int p = blockIdx.x;
  const int tid = threadIdx.x;
  const int w = tid >> 6, lg = (tid >> 4) & 3, li = tid & 15;
  const int l = tid & 63;
  const int r32 = l & 31, kh = (l >> 5)*8;

  extern __shared__ char smem[];
  float*    gate_s = (float*)smem;                 // 128 B
  _Float16* gm_s   = (_Float16*)(smem + 128);      // [2][16][264]
  float*    lg2    = (float*)(smem + 17024);       // [2][16][24]
  _Float16* P2     = (_Float16*)(smem + 20096);    // [2][16][40]
  _Float16* outp   = (_Float16*)(smem + 22656);    // [2][16][264]
  _Float16* x3_s   = (_Float16*)(smem + 39552);    // [2][16][264]
  _Float16* Vtall  = (_Float16*)(smem + 56448);    // [2][256][40]
  _Float16* Qall   = (_Float16*)(smem + 97408);    // [2][16][264]
  _Float16* Kall   = (_Float16*)(smem + 114304);   // [2][16][264]
  _Float16* cat_s  = (_Float16*)(smem + 97408);    // overlay [2][16][520]

  if (tid < 32){
    int it = tid >> 4, q = tid & 15;
    gate_s[it*16 + q] = gate[(size_t)(2*p + it)*16 + q];
  }
  __syncthreads();
#pragma unroll
  for (int it = 0; it < 2; ++it){
    const int b = 2*p + it;
    for (int idx = tid; idx < 4096; idx += 512){
      int q = idx >> 8, d = idx & 255;
      gm_s[it*4224 + q*264 + d] = (_Float16)(x2m[((size_t)b*16 + q)*256 + d] * gate_s[it*16 + q]);
    }
  }
  for (int idx = tid; idx < 10240; idx += 512) ((unsigned*)Vtall)[idx] = 0u;
  for (int idx = tid; idx < 2*16*40; idx += 512) P2[idx] = (_Float16)0.f;
  __syncthreads();

  { // QKVall = gm_stacked(32x256) @ GMIN(768x256); wave -> n-tiles {3w..3w+2}
    const int itq = r32 >> 4, qr = r32 & 15;
#pragma unroll
    for (int s = 0; s < 3; ++s){
      int nt = 3*w + s;
      f32x16 acc = 0.f;
      for (int kk = 0; kk < 16; ++kk){
        f16x8 A = *(const f16x8*)(gm_s + itq*4224 + qr*264 + kk*16 + kh);
        f16x8 B = *(const f16x8*)(GMIN + (size_t)(nt*32 + r32)*256 + kk*16 + kh);
        acc = mfma32(A, B, acc);
      }
      int sec = nt >> 3;                   // 0=q, 1=k, 2=v (wave-uniform)
      int hcol = (nt & 7)*32 + r32;        // head-dim column 0..255
#pragma unroll
      for (int reg = 0; reg < 16; ++reg){
        int row = (reg & 3) + 8*(reg >> 2) + 4*(l >> 5);
        int it2 = row >> 4, q2 = row & 15;
        _Float16 v = (_Float16)acc[reg];
        if (sec == 0)      Qall[it2*4224 + q2*264 + hcol] = v;
        else if (sec == 1) Kall[it2*4224 + q2*264 + hcol] = v;
        else               Vtall[it2*10240 + hcol*40 + q2] = v;
      }
    }
  }
  __syncthreads();

  for (int h = 0; h < 4; ++h){
    if (w < 2){ // 16x16 logits; wave w -> item w
      const int it = w, b = 2*p + it;
      f32x4 acc = 0.f;
#pragma unroll
      for (int kk = 0; kk < 2; ++kk){
        f16x8 A = *(const f16x8*)(Qall + it*4224 + li*264 + 64*h + kk*32 + lg*8);
        f16x8 B = *(const f16x8*)(Kall + it*4224 + li*264 + 64*h + kk*32 + lg*8);
        acc = mfma16(A, B, acc);
      }
      float amk = em[(size_t)b*64 + li];
#pragma unroll
      for (int j = 0; j < 4; ++j){
        int q = 4*lg + j;
        float amq = em[(size_t)b*64 + q];
        float m = 1.f - (1.f - amq)*(1.f - amk);
        float v = acc[j]*0.125f;
        if (m > 0.f) v = -1e9f;
        lg2[it*384 + q*24 + li] = v;
      }
    }
    __syncthreads();
    if (tid < 256){ // softmax, both items
      int q = tid >> 4, key = tid & 15;
#pragma unroll
      for (int it = 0; it < 2; ++it){
        const int b = 2*p + it;
        float v = lg2[it*384 + q*24 + key];
        float mx = v;
#pragma unroll
        for (int d = 1; d < 16; d <<= 1) mx = fmaxf(mx, __shfl_xor(mx, d, 16));
        float pe = expf(v - mx);
        float s = pe;
#pragma unroll
        for (int d = 1; d < 16; d <<= 1) s += __shfl_xor(s, d, 16);
        float amq = em[(size_t)b*64 + q], amk = em[(size_t)b*64 + key];
        float m = 1.f - (1.f - amq)*(1.f - amk);
        P2[it*640 + q*40 + key] = (_Float16)((pe/s)*(1.f - m));
      }
    }
    __syncthreads();
    { // PV: 8 waves = 2 items x 4 dim-tiles
      const int it = w & 1, dt = w >> 1;
      f32x4 acc = 0.f;
      f16x8 A = *(const f16x8*)(P2 + it*640 + li*40 + lg*8);
      f16x8 B = *(const f16x8*)(Vtall + it*10240 + (size_t)(64*h + 16*dt + li)*40 + lg*8);
      acc = mfma16(A, B, acc);
#pragma unroll
      for (int j = 0; j < 4; ++j)
        outp[it*4224 + (4*lg + j)*264 + 64*h + 16*dt + li] = (_Float16)acc[j];
    }
    __syncthreads();
  }
  { // gmsg out-proj stacked M=32; wave -> n-tile w; also stage x2 -> cat
    const int ito = r32 >> 4, qr = r32 & 15;
    {
      int nt = w;
      f32x16 acc = 0.f;
      for (int kk = 0; kk < 16; ++kk){
        f16x8 A = *(const f16x8*)(outp + ito*4224 + qr*264 + kk*16 + kh);
        f16x8 B = *(const f16x8*)(GMOUT + (size_t)(nt*32 + r32)*256 + kk*16 + kh);
        acc = mfma32(A, B, acc);
      }
      int col = nt*32 + r32;
      float bias = gob[col];
#pragma unroll
      for (int reg = 0; reg < 16; ++reg){
        int row = (reg & 3) + 8*(reg >> 2) + 4*(l >> 5);
        int it2 = row >> 4, q2 = row & 15;
        float m = 1.f - em[(size_t)(2*p + it2)*64 + q2];
        cat_s[it2*8320 + q2*520 + 256 + col] = (_Float16)((acc[reg] + bias)*m);
      }
    }
#pragma unroll
    for (int it = 0; it < 2; ++it){
      const int b = 2*p + it;
      for (int idx = tid; idx < 4096; idx += 512){
        int q = idx >> 8, d = idx & 255;
        cat_s[it*8320 + q*520 + d] = (_Float16)(x2[((size_t)b*16 + q)*256 + d]);
      }
    }
  }
  __syncthreads();
  { // x3 = relu(cat @ fc2 + b) stacked M=32; wave -> n-tile w, K=512
    const int ito = r32 >> 4, qr = r32 & 15;
    int nt = w;
    f32x16 acc = 0.f;
    for (int kk = 0; kk < 32; ++kk){
      f16x8 A = *(const f16x8*)(cat_s + ito*8320 + qr*520 + kk*16 + kh);
      f16x8 B = *(const f16x8*)(FC2T + (size_t)(nt*32 + r32)*512 + kk*16 + kh);
      acc = mfma32(A, B, acc);
    }
    int col = nt*32 + r32;
    float bias = fc2b[col];
#pragma unroll
    for (int reg = 0; reg < 16; ++reg){
      int row = (reg & 3) + 8*(reg >> 2) + 4*(l >> 5);
      int it2 = row >> 4, q2 = row & 15;
      x3_s[it2*4224 + q2*264 + col] = (_Float16)fmaxf(acc[reg] + bias, 0.f);
    }
  }
  __syncthreads();
  { // gi stacked M=32; wave -> n-tiles {3w..3w+2}, N=768
    const int r0 = ((2*p) >> 6)*16, t0 = (2*p) & 63;
    const int ito = r32 >> 4, qr = r32 & 15;
#pragma unroll
    for (int s = 0; s < 3; ++s){
      int nt = 3*w + s;
      f32x16 acc = 0.f;
      for (int kk = 0; kk < 16; ++kk){
        f16x8 A = *(const f16x8*)(x3_s + ito*4224 + qr*264 + kk*16 + kh);
        f16x8 B = *(const f16x8*)(GIHT + (size_t)(nt*32 + r32)*256 + kk*16 + kh);
        acc = mfma32(A, B, acc);
      }
      int col = nt*32 + r32;
      float bias = gib[col];
#pragma unroll
      for (int reg = 0; reg < 16; ++reg){
        int row = (reg & 3) + 8*(reg >> 2) + 4*(l >> 5);
        int it2 = row >> 4, q2 = row & 15;
        gi[((size_t)((r0 + q2)*64 + t0 + it2))*768 + col] = acc[reg] + bias;
      }
    }
  }
}

// ------------------------------------------------------------------ K3: GRU
// 512 threads = 8 waves x 6 col-tiles (r18/r19-verified; r21's prefetch
// variant spilled and regressed — reverted).
__global__ __launch_bounds__(512) void k3_gru(
    const _Float16* __restrict__ WHH, const float* __restrict__ bhh,
    const float* __restrict__ gi, const float* __restrict__ h0,
    float* __restrict__ hs)
{
  const int rb = blockIdx.x;
  const int row0 = rb * 16;
  const int tid = threadIdx.x;
  const int w = tid >> 6, lg = (tid >> 4) & 3, li = tid & 15;

  extern __shared__ char smem3[];
  _Float16* hf16 = (_Float16*)smem3;
  float* hf32 = (float*)(smem3 + 8448);
  float* gh   = (float*)(smem3 + 8448 + 16640);
  float* bhs  = (float*)(smem3 + 8448 + 16640 + 49664);

  for (int idx = tid; idx < 768; idx += 512) bhs[idx] = bhh[idx];
  for (int idx = tid; idx < 4096; idx += 512){
    int r = idx >> 8, d = idx & 255;
    float v = h0[(size_t)(row0 + r)*256 + d];
    hf32[r*260 + d] = v;
    hf16[r*264 + d] = (_Float16)v;
  }
  __syncthreads();

  const int er = tid >> 5;
  const int dd = (tid & 31) * 8;

  for (int t = 0; t < 64; ++t){
    const float* gp = gi + ((size_t)(row0 + er)*64 + t)*768 + dd;
    f32x4 gr[2], gz[2], gn[2];
#pragma unroll
    for (int v = 0; v < 2; ++v){
      gr[v] = *(const f32x4*)(gp + v*4);
      gz[v] = *(const f32x4*)(gp + 256 + v*4);
      gn[v] = *(const f32x4*)(gp + 512 + v*4);
    }
    f16x8 a[8];
#pragma unroll
    for (int kk = 0; kk < 8; ++kk)
      a[kk] = *(const f16x8*)(hf16 + li*264 + kk*32 + lg*8);
    f32x4 acc[6];
#pragma unroll
    for (int c = 0; c < 6; ++c) acc[c] = 0.f;
#pragma unroll
    for (int c = 0; c < 6; ++c){
      const _Float16* bp = WHH + (size_t)(w*96 + c*16 + li)*256 + lg*8;
#pragma unroll
      for (int kk = 0; kk < 8; ++kk)
        acc[c] = mfma16(a[kk], *(const f16x8*)(bp + kk*32), acc[c]);
    }
#pragma unroll
    for (int c = 0; c < 6; ++c){
      int col = w*96 + c*16 + li;
#pragma unroll
      for (int j = 0; j < 4; ++j)
        gh[(4*lg + j)*776 + col] = acc[c][j];
    }
    __syncthreads();
    {
      float* hp32 = hf32 + er*260 + dd;
      float* hsp  = hs + ((size_t)(rb*64 + t)*16 + er)*256 + dd;
      f16x8 hv8;
#pragma unroll
      for (int v = 0; v < 2; ++v){
        f32x4 xr = *(const f32x4*)(gh + er*776 +       dd + v*4);
        f32x4 xz = *(const f32x4*)(gh + er*776 + 256 + dd + v*4);
        f32x4 xn = *(const f32x4*)(gh + er*776 + 512 + dd + v*4);
        f32x4 hold = *(const f32x4*)(hp32 + v*4);
        f32x4 hout;
#pragma unroll
        for (int e = 0; e < 4; ++e){
          int d = dd + v*4 + e;
          float rr_ = 1.f/(1.f + __expf(-(gr[v][e] + xr[e] + bhs[d])));
          float zz  = 1.f/(1.f + __expf(-(gz[v][e] + xz[e] + bhs[256 + d])));
          float pre = gn[v][e] + rr_*(xn[e] + bhs[512 + d]);
          float nn  = 1.f - 2.f/(1.f + __expf(2.f*pre));
          float hv = (1.f - zz)*nn + zz*hold[e];
          hout[e] = hv;
          hv8[v*4 + e] = (_Float16)hv;
        }
        *(f32x4*)(hp32 + v*4) = hout;
        *(f32x4*)(hsp + v*4)  = hout;
      }
      *(f16x8*)(hf16 + er*264 + dd) = hv8;
    }
    __syncthreads();
  }
}

// ------------------------------------------------------------------ K4: q out
__global__ __launch_bounds__(256) void k4_q(
    const _Float16* __restrict__ FC3T, const float* __restrict__ fc3b,
    const float* __restrict__ em, const float* __restrict__ hs, float* __restrict__ qo)
{
  const int tid = threadIdx.x;
  const int w = tid >> 6, lg = (tid >> 4) & 3, li = tid & 15;
  const int rb = blockIdx.x*64 + 16*w;
  f32x4 acc[2];
#pragma unroll
  for (int c = 0; c < 2; ++c) acc[c] = 0.f;
  for (int kk = 0; kk < 8; ++kk){
    const float* ap = hs + (size_t)(rb + li)*256 + kk*32 + lg*8;
    f32x4 v0 = *(const f32x4*)ap, v1 = *(const f32x4*)(ap + 4);
    f16x8 A;
#pragma unroll
    for (int e = 0; e < 4; ++e){ A[e] = (_Float16)v0[e]; A[e+4] = (_Float16)v1[e]; }
#pragma unroll
    for (int c = 0; c < 2; ++c){
      f16x8 B = *(const f16x8*)(FC3T + (size_t)(16*c + li)*256 + kk*32 + lg*8);
      acc[c] = mfma16(A, B, acc[c]);
    }
  }
#pragma unroll
  for (int c = 0; c < 2; ++c){
    int col = 16*c + li;
    float bias = fc3b[col];
#pragma unroll
    for (int j = 0; j < 4; ++j){
      int row = rb + 4*lg + j;
      float am = em[(size_t)(row >> 4)*64 + (row & 15)];
      qo[(size_t)row*32 + col] = (acc[c][j] + bias)*(1.f - am);
    }
  }
}

// --------------------------------------------------------------------- launch
extern "C" void kernel_launch(void* const* d_in, const int* in_sizes, int n_in,
                              void* d_out, int out_size, void* d_ws, size_t ws_size,
                              hipStream_t stream)
{
  constexpr size_t OFF_FC1T   = 0;
  constexpr size_t OFF_MSG1T  = 49152;
  constexpr size_t OFF_AINT   = 98304;
  constexpr size_t OFF_LINT   = 491520;
  constexpr size_t OFF_AOUTT  = 884736;
  constexpr size_t OFF_LOUTT  = 1015808;
  constexpr size_t OFF_GMINT  = 1146880;
  constexpr size_t OFF_GMOUTT = 1540096;
  constexpr size_t OFF_FC2T   = 1671168;
  constexpr size_t OFF_GIHT   = 1933312;
  constexpr size_t OFF_GHHT   = 2326528;
  constexpr size_t OFF_FC3T   = 2719744;
  constexpr size_t OFF_G1T    = 2736128;
  constexpr size_t OFF_GINT   = 2834432;
  constexpr size_t OFF_WVEFF  = 3620864;
  constexpr size_t OFF_BEFF   = 3637248;
  constexpr size_t OFF_GATE   = 3637504;
  constexpr size_t OFF_X2     = 3768576;
  constexpr size_t OFF_X2M    = 37323008;
  constexpr size_t OFF_GI     = 70877440;
  constexpr size_t NEED       = 171540736;
  if (ws_size < NEED) return;

  char* ws = (char*)d_ws;
  const float* ent = (const float*)d_in[0];
  const float* om  = (const float*)d_in[1];
  const float* em  = (const float*)d_in[2];

  WJobs jb{};
  int nj = 0;
  auto addj = [&](int src_idx, size_t off, int K, int N, int m){
    jb.src[nj] = (const float*)d_in[src_idx]; jb.off[nj] = (unsigned)off;
    jb.K[nj] = K; jb.N[nj] = N; jb.mode[nj] = m; ++nj;
  };
  addj(4,  OFF_FC1T,   96, 256, 0);
  addj(17, OFF_MSG1T,  96, 256, 0);
  addj(6,  OFF_AINT,  256, 768, 0);
  addj(19, OFF_LINT,  256, 768, 0);
  addj(7,  OFF_AOUTT, 256, 256, 0);
  addj(20, OFF_LOUTT, 256, 256, 0);
  addj(22, OFF_GMINT, 256, 768, 0);
  addj(23, OFF_GMOUTT,256, 256, 0);
  addj(9,  OFF_FC2T,  512, 256, 0);
  addj(11, OFF_GIHT,  256, 768, 0);
  addj(12, OFF_GHHT,  256, 768, 0);
  addj(15, OFF_FC3T,  256,  32, 0);
  addj(28, OFF_G1T,    96, 256, 1);
  addj(25, OFF_GINT,  256, 768, 1);
  k0_conv<<<dim3(96, nj), 256, 0, stream>>>(jb, ws);

  k0w_gate<<<1, 256, 0, stream>>>(
      (const float*)d_in[26], (const float*)d_in[30],
      (const float*)d_in[27], (const float*)d_in[25],
      (_Float16*)(ws + OFF_WVEFF), (float*)(ws + OFF_BEFF));

  constexpr int SMB = 156672, SMK2 = 131200, SM3 = 77824;
  (void)hipFuncSetAttribute(reinterpret_cast<const void*>(&k1_all),
                            hipFuncAttributeMaxDynamicSharedMemorySize, SMB);
  (void)hipFuncSetAttribute(reinterpret_cast<const void*>(&k2_global),
                            hipFuncAttributeMaxDynamicSharedMemorySize, SMK2);
  (void)hipFuncSetAttribute(reinterpret_cast<const void*>(&k3_gru),
                            hipFuncAttributeMaxDynamicSharedMemorySize, SM3);

  float* qout = (float*)d_out;
  float* hsout = qout + 1048576;
  float* gout = qout + 9437184;

  k1_all<<<4096, 512, SMB, stream>>>(ent, om, em,
      (const _Float16*)(ws + OFF_FC1T),  (const float*)d_in[5],
      (const _Float16*)(ws + OFF_AINT),
      (const _Float16*)(ws + OFF_AOUTT), (const float*)d_in[8],
      (float*)(ws + OFF_X2),
      (const _Float16*)(ws + OFF_MSG1T), (const float*)d_in[18],
      (const _Float16*)(ws + OFF_LINT),
      (const _Float16*)(ws + OFF_LOUTT), (const float*)d_in[21],
      (float*)(ws + OFF_X2M),
      (const _Float16*)(ws + OFF_G1T),   (const float*)d_in[29],
      (const _Float16*)(ws + OFF_GINT),
      (const _Float16*)(ws + OFF_WVEFF),
      (const float*)(ws + OFF_BEFF), (const float*)d_in[31],
      gout, (float*)(ws + OFF_GATE));

  k2_global<<<1024, 512, SMK2, stream>>>(em,
      (const float*)(ws + OFF_X2), (const float*)(ws + OFF_X2M),
      (const float*)(ws + OFF_GATE),
      (const _Float16*)(ws + OFF_GMINT), (const _Float16*)(ws + OFF_GMOUTT), (const float*)d_in[24],
      (const _Float16*)(ws + OFF_FC2T), (const float*)d_in[10],
      (const _Float16*)(ws + OFF_GIHT), (const float*)d_in[13],
      (float*)(ws + OFF_GI));

  k3_gru<<<32, 512, SM3, stream>>>(
      (const _Float16*)(ws + OFF_GHHT), (const float*)d_in[14],
      (const float*)(ws + OFF_GI), (const float*)d_in[3], hsout);

  k4_q<<<512, 256, 0, stream>>>(
      (const _Float16*)(ws + OFF_FC3T), (const float*)d_in[16],
      em, hsout, qout);
}